// Round 1
// baseline (1966.419 us; speedup 1.0000x reference)
//
#include <hip/hip_runtime.h>
#include <hip/hip_bf16.h>

using bf16 = __hip_bfloat16;

#define DEVI __device__ __forceinline__

constexpr int B = 4, C = 128, C2 = 256, H = 96, W = 256;
constexpr int HW = H * W;            // 24576
constexpr int NPIX = B * HW;         // 98304
constexpr float SCALE = 0.08838834764831845f; // 128^-0.5
constexpr float LN_EPS = 1e-5f;

DEVI float b2f(bf16 v) { return __bfloat162float(v); }
DEVI bf16 f2b(float v) { return __float2bfloat16(v); }

// ---------------------------------------------------------------------------
// K1: conv1x1  y[b,o,h,w] = sum_c W[o,c] * x[b,c,h,w]   (OC = 256)
// Block: 256 thr, 128 pixels. LDS-stage x tile [128c][128px] fp32.
// Each thread: px = t&127, oc-half = t>>7 (wave-uniform), 16 groups of 8 oc.
// ---------------------------------------------------------------------------
template <int OC>
__global__ __launch_bounds__(256) void conv1x1_kernel(
    const float* __restrict__ x,   // [B,C,H,W]
    const float* __restrict__ Wm,  // [OC,C]
    bf16* __restrict__ y)          // [B,OC,H,W]
{
    __shared__ float xs[C][128];
    const int t = threadIdx.x;
    const int pb = blockIdx.x * 128;
    const int b = pb / HW;
    const int hw0 = pb % HW;

    for (int idx = t; idx < C * 128; idx += 256) {
        int c = idx >> 7, px = idx & 127;
        xs[c][px] = x[(b * C + c) * HW + hw0 + px];
    }
    __syncthreads();

    const int px = t & 127;
    const int half = t >> 7;           // wave-uniform
    const int hw = hw0 + px;
    constexpr int NG = OC / 16;        // groups of 8 per half

    for (int og = 0; og < NG; ++og) {
        const int ocb = half * (OC / 2) + og * 8;
        float acc[8] = {};
        const float* wrow = Wm + ocb * C;
        for (int c = 0; c < C; ++c) {
            float xv = xs[c][px];
#pragma unroll
            for (int j = 0; j < 8; ++j)
                acc[j] = fmaf(wrow[j * C + c], xv, acc[j]);
        }
#pragma unroll
        for (int j = 0; j < 8; ++j)
            y[(b * OC + ocb + j) * HW + hw] = f2b(acc[j]);
    }
}

// ---------------------------------------------------------------------------
// K2: depthwise 3x3, SAME zero padding, cross-correlation (XLA semantics)
// ---------------------------------------------------------------------------
__global__ __launch_bounds__(256) void dwconv_kernel(
    const bf16* __restrict__ y,   // [B,C2,H,W]
    const float* __restrict__ k,  // [C2,9]
    bf16* __restrict__ out)       // [B,C2,H,W]
{
    int idx = blockIdx.x * 256 + threadIdx.x;
    int hw = idx % HW;
    int bc = idx / HW;
    int h = hw >> 8, w = hw & 255;
    const bf16* yb = y + (size_t)bc * HW;
    const float* kk = k + (bc & (C2 - 1)) * 9;
    float acc = 0.f;
#pragma unroll
    for (int i = 0; i < 3; ++i) {
        int hh = h + i - 1;
        if ((unsigned)hh >= (unsigned)H) continue;
#pragma unroll
        for (int j = 0; j < 3; ++j) {
            int ww = w + j - 1;
            if ((unsigned)ww >= (unsigned)W) continue;
            acc = fmaf(b2f(yb[hh * W + ww]), kk[i * 3 + j], acc);
        }
    }
    out[idx] = f2b(acc);
}

// ---------------------------------------------------------------------------
// K3: LayerNorm over C (on mid = channels [C, 2C) of fusion) + conv1x1 Q
// ---------------------------------------------------------------------------
__global__ __launch_bounds__(256) void lnq_kernel(
    const bf16* __restrict__ fusion,  // [B,C2,H,W]
    const float* __restrict__ lnw, const float* __restrict__ lnb,
    const float* __restrict__ Wq,     // [C,C]
    const float* __restrict__ bq,     // [C]
    bf16* __restrict__ q)             // [B,C,H,W]
{
    __shared__ bf16 xs[C][128];
    __shared__ float red[2][2][128];
    __shared__ float muA[128], rsA[128];
    const int t = threadIdx.x;
    const int pb = blockIdx.x * 128;
    const int b = pb / HW;
    const int hw0 = pb % HW;

    for (int idx = t; idx < C * 128; idx += 256) {
        int c = idx >> 7, px = idx & 127;
        xs[c][px] = fusion[(b * C2 + C + c) * HW + hw0 + px];
    }
    __syncthreads();

    const int px = t & 127;
    const int half = t >> 7;
    // stats: 2 threads per pixel, 64 channels each
    float s1 = 0.f, s2 = 0.f;
    for (int c = half * 64; c < half * 64 + 64; ++c) {
        float v = b2f(xs[c][px]);
        s1 += v; s2 += v * v;
    }
    red[half][0][px] = s1;
    red[half][1][px] = s2;
    __syncthreads();
    if (t < 128) {
        float S1 = red[0][0][t] + red[1][0][t];
        float S2 = red[0][1][t] + red[1][1][t];
        float mu = S1 * (1.f / C);
        float var = S2 * (1.f / C) - mu * mu;
        muA[t] = mu;
        rsA[t] = rsqrtf(var + LN_EPS);
    }
    __syncthreads();
    for (int idx = t; idx < C * 128; idx += 256) {
        int c = idx >> 7, p2 = idx & 127;
        float v = b2f(xs[c][p2]);
        v = (v - muA[p2]) * rsA[p2] * lnw[c] + lnb[c];
        xs[c][p2] = f2b(v);
    }
    __syncthreads();

    // GEMM: OC = 128, halves of 64, 8 groups of 8
    for (int og = 0; og < 8; ++og) {
        const int ocb = half * 64 + og * 8;
        float acc[8] = {};
        const float* wrow = Wq + ocb * C;
        for (int c = 0; c < C; ++c) {
            float xv = b2f(xs[c][px]);
#pragma unroll
            for (int j = 0; j < 8; ++j)
                acc[j] = fmaf(wrow[j * C + c], xv, acc[j]);
        }
#pragma unroll
        for (int j = 0; j < 8; ++j)
            q[(b * C + ocb + j) * HW + hw0 + px] = f2b(acc[j] + bq[ocb + j]);
    }
}

// ---------------------------------------------------------------------------
// K4: attn[bh, w, v] = SCALE * sum_c Ql[c,w] * Qr[c,v]   (64x64 tile/block)
// ---------------------------------------------------------------------------
__global__ __launch_bounds__(256) void attn_kernel(
    const bf16* __restrict__ ql, const bf16* __restrict__ qr,
    float* __restrict__ attn)   // [B*H, W, W]
{
    __shared__ float Als[C][64];
    __shared__ float Bls[C][64];
    const int t = threadIdx.x;
    const int blk = blockIdx.x;
    const int bh = blk >> 4;
    const int tile = blk & 15;
    const int w0 = (tile >> 2) * 64, v0 = (tile & 3) * 64;
    const int b = bh / H, h = bh % H;
    const bf16* qlb = ql + (size_t)(b * C) * HW + h * W;
    const bf16* qrb = qr + (size_t)(b * C) * HW + h * W;

    for (int idx = t; idx < C * 64; idx += 256) {
        int c = idx >> 6, u = idx & 63;
        Als[c][u] = b2f(qlb[c * HW + w0 + u]);
        Bls[c][u] = b2f(qrb[c * HW + v0 + u]);
    }
    __syncthreads();

    const int tv = (t & 15) * 4, tw = (t >> 4) * 4;
    float acc[4][4] = {};
    for (int c = 0; c < C; ++c) {
        const float4 av = *reinterpret_cast<const float4*>(&Als[c][tw]);
        const float4 bv = *reinterpret_cast<const float4*>(&Bls[c][tv]);
        const float a[4] = {av.x, av.y, av.z, av.w};
        const float bb[4] = {bv.x, bv.y, bv.z, bv.w};
#pragma unroll
        for (int i = 0; i < 4; ++i)
#pragma unroll
            for (int j = 0; j < 4; ++j)
                acc[i][j] = fmaf(a[i], bb[j], acc[i][j]);
    }
    float* ap = attn + ((size_t)bh * W + w0 + tw) * W + v0 + tv;
#pragma unroll
    for (int i = 0; i < 4; ++i)
#pragma unroll
        for (int j = 0; j < 4; ++j)
            ap[i * W + j] = acc[i][j] * SCALE;
}

// ---------------------------------------------------------------------------
// K5a: row softmax stats (max & sumexp over v), one wave per row
// ---------------------------------------------------------------------------
__global__ __launch_bounds__(256) void rowstats_kernel(
    const float* __restrict__ attn, float* __restrict__ mrow, float* __restrict__ srow)
{
    const int gw = blockIdx.x * 4 + (threadIdx.x >> 6);  // row id in [0, B*H*W)
    const int lane = threadIdx.x & 63;
    const float* row = attn + (size_t)gw * W;
    float a0 = row[lane], a1 = row[lane + 64], a2 = row[lane + 128], a3 = row[lane + 192];
    float m = fmaxf(fmaxf(a0, a1), fmaxf(a2, a3));
#pragma unroll
    for (int off = 32; off; off >>= 1) m = fmaxf(m, __shfl_xor(m, off));
    float s = expf(a0 - m) + expf(a1 - m) + expf(a2 - m) + expf(a3 - m);
#pragma unroll
    for (int off = 32; off; off >>= 1) s += __shfl_xor(s, off);
    if (lane == 0) { mrow[gw] = m; srow[gw] = s; }
}

// ---------------------------------------------------------------------------
// K5b: col softmax stats (max & sumexp over w), one block per (b,h), thread=v
// ---------------------------------------------------------------------------
__global__ __launch_bounds__(256) void colstats_kernel(
    const float* __restrict__ attn, float* __restrict__ mcol, float* __restrict__ scol)
{
    const int bh = blockIdx.x;
    const int v = threadIdx.x;
    const float* base = attn + (size_t)bh * W * W + v;
    float m = -1e30f, s = 0.f;
    for (int w = 0; w < W; ++w) {
        float a = base[w * W];
        float nm = fmaxf(m, a);
        s = s * expf(m - nm) + expf(a - nm);
        m = nm;
    }
    mcol[bh * W + v] = m;
    scol[bh * W + v] = s;
}

// ---------------------------------------------------------------------------
// K6: out_l[b,c,h,w] = x_l + beta[c] * (1/srow[w]) * sum_v e^(a[w,v]-mrow[w]) Vr[c,v]
// Block: (b,h) x 64-w tile; loop v in chunks of 64.
// ---------------------------------------------------------------------------
__global__ __launch_bounds__(256) void outl_kernel(
    const float* __restrict__ attn,
    const bf16* __restrict__ fusion_r,   // V_r = channels [0,C)
    const float* __restrict__ mrow, const float* __restrict__ srow,
    const float* __restrict__ xl, const float* __restrict__ beta,
    float* __restrict__ outl)
{
    __shared__ float Vls[C][64];      // V_r chunk [c][v]
    __shared__ float Pls[64][65];     // exp chunk [w][v], padded
    const int t = threadIdx.x;
    const int bh = blockIdx.x >> 2;
    const int w0 = (blockIdx.x & 3) * 64;
    const int b = bh / H, h = bh % H;
    const int wq = t & 15, cq = t >> 4;
    float acc[8][4] = {};

    for (int v0 = 0; v0 < W; v0 += 64) {
        __syncthreads();
        for (int idx = t; idx < C * 64; idx += 256) {
            int c = idx >> 6, u = idx & 63;
            Vls[c][u] = b2f(fusion_r[(size_t)(b * C2 + c) * HW + h * W + v0 + u]);
        }
        for (int idx = t; idx < 64 * 64; idx += 256) {
            int wl = idx >> 6, u = idx & 63;
            float a = attn[((size_t)bh * W + w0 + wl) * W + v0 + u];
            Pls[wl][u] = expf(a - mrow[bh * W + w0 + wl]);
        }
        __syncthreads();
        for (int v = 0; v < 64; ++v) {
            float bb[4];
#pragma unroll
            for (int j = 0; j < 4; ++j) bb[j] = Pls[wq * 4 + j][v];
#pragma unroll
            for (int i = 0; i < 8; ++i) {
                float av = Vls[cq * 8 + i][v];
#pragma unroll
                for (int j = 0; j < 4; ++j)
                    acc[i][j] = fmaf(av, bb[j], acc[i][j]);
            }
        }
    }
#pragma unroll
    for (int i = 0; i < 8; ++i) {
        int c = cq * 8 + i;
        float bt = beta[c];
#pragma unroll
        for (int j = 0; j < 4; ++j) {
            int w = w0 + wq * 4 + j;
            float r = acc[i][j] / srow[bh * W + w];
            size_t o = (size_t)(b * C + c) * HW + h * W + w;
            outl[o] = xl[o] + r * bt;
        }
    }
}

// ---------------------------------------------------------------------------
// K7: out_r[b,c,h,v] = x_r + gamma[c] * (1/scol[v]) * sum_w e^(a[w,v]-mcol[v]) Vl[c,w]
// ---------------------------------------------------------------------------
__global__ __launch_bounds__(256) void outr_kernel(
    const float* __restrict__ attn,
    const bf16* __restrict__ fusion_l,   // V_l = channels [0,C)
    const float* __restrict__ mcol, const float* __restrict__ scol,
    const float* __restrict__ xr, const float* __restrict__ gamma,
    float* __restrict__ outr)
{
    __shared__ float Vls[C][64];      // V_l chunk [c][w]
    __shared__ float Pls[64][68];     // exp chunk [w][v], padded for float4
    const int t = threadIdx.x;
    const int bh = blockIdx.x >> 2;
    const int v0 = (blockIdx.x & 3) * 64;
    const int b = bh / H, h = bh % H;
    const int vq = t & 15, cq = t >> 4;
    float acc[8][4] = {};

    for (int w0 = 0; w0 < W; w0 += 64) {
        __syncthreads();
        for (int idx = t; idx < C * 64; idx += 256) {
            int c = idx >> 6, u = idx & 63;
            Vls[c][u] = b2f(fusion_l[(size_t)(b * C2 + c) * HW + h * W + w0 + u]);
        }
        for (int idx = t; idx < 64 * 64; idx += 256) {
            int wl = idx >> 6, u = idx & 63;
            float a = attn[((size_t)bh * W + w0 + wl) * W + v0 + u];
            Pls[wl][u] = expf(a - mcol[bh * W + v0 + u]);
        }
        __syncthreads();
        for (int w = 0; w < 64; ++w) {
            const float4 bv = *reinterpret_cast<const float4*>(&Pls[w][vq * 4]);
            const float bb[4] = {bv.x, bv.y, bv.z, bv.w};
#pragma unroll
            for (int i = 0; i < 8; ++i) {
                float av = Vls[cq * 8 + i][w];
#pragma unroll
                for (int j = 0; j < 4; ++j)
                    acc[i][j] = fmaf(av, bb[j], acc[i][j]);
            }
        }
    }
#pragma unroll
    for (int i = 0; i < 8; ++i) {
        int c = cq * 8 + i;
        float g = gamma[c];
#pragma unroll
        for (int j = 0; j < 4; ++j) {
            int v = v0 + vq * 4 + j;
            float r = acc[i][j] / scol[bh * W + v];
            size_t o = (size_t)(b * C + c) * HW + h * W + v;
            outr[o] = xr[o] + r * g;
        }
    }
}

// ---------------------------------------------------------------------------
extern "C" void kernel_launch(void* const* d_in, const int* in_sizes, int n_in,
                              void* d_out, int out_size, void* d_ws, size_t ws_size,
                              hipStream_t stream) {
    (void)in_sizes; (void)n_in; (void)out_size; (void)ws_size;
    const float* x_l  = (const float*)d_in[0];
    const float* x_r  = (const float*)d_in[1];
    const float* Wl_m = (const float*)d_in[2];
    const float* Wr_m = (const float*)d_in[3];
    const float* dw_l = (const float*)d_in[4];
    const float* dw_r = (const float*)d_in[5];
    const float* lnl_w = (const float*)d_in[6];
    const float* lnl_b = (const float*)d_in[7];
    const float* lnr_w = (const float*)d_in[8];
    const float* lnr_b = (const float*)d_in[9];
    const float* Wq_l = (const float*)d_in[10];
    const float* bq_l = (const float*)d_in[11];
    const float* Wq_r = (const float*)d_in[12];
    const float* bq_r = (const float*)d_in[13];
    const float* beta  = (const float*)d_in[14];
    const float* gamma = (const float*)d_in[15];

    char* ws = (char*)d_ws;
    // byte offsets
    bf16* fusion_l = (bf16*)(ws + 0);                  // 50,331,648 B
    bf16* fusion_r = (bf16*)(ws + 50331648);           // 50,331,648 B
    bf16* Q_l      = (bf16*)(ws + 100663296);          // 25,165,824 B
    bf16* Q_r      = (bf16*)(ws + 125829120);          // 25,165,824 B
    float* attn    = (float*)(ws + 150994944);         // 100,663,296 B
    bf16* Ytmp     = (bf16*)(ws + 150994944);          // aliases attn (dead before attn written)
    float* mrow    = (float*)(ws + 251658240);
    float* srow    = (float*)(ws + 252051456);
    float* mcol    = (float*)(ws + 252444672);
    float* scol    = (float*)(ws + 252837888);

    float* out_l = (float*)d_out;
    float* out_r = out_l + (size_t)B * C * HW;

    const dim3 blk(256);

    conv1x1_kernel<C2><<<NPIX / 128, blk, 0, stream>>>(x_l, Wl_m, Ytmp);
    dwconv_kernel<<<(B * C2 * HW) / 256, blk, 0, stream>>>(Ytmp, dw_l, fusion_l);
    conv1x1_kernel<C2><<<NPIX / 128, blk, 0, stream>>>(x_r, Wr_m, Ytmp);
    dwconv_kernel<<<(B * C2 * HW) / 256, blk, 0, stream>>>(Ytmp, dw_r, fusion_r);

    lnq_kernel<<<NPIX / 128, blk, 0, stream>>>(fusion_l, lnl_w, lnl_b, Wq_l, bq_l, Q_l);
    lnq_kernel<<<NPIX / 128, blk, 0, stream>>>(fusion_r, lnr_w, lnr_b, Wq_r, bq_r, Q_r);

    attn_kernel<<<B * H * 16, blk, 0, stream>>>(Q_l, Q_r, attn);

    rowstats_kernel<<<NPIX / 4, blk, 0, stream>>>(attn, mrow, srow);
    colstats_kernel<<<B * H, blk, 0, stream>>>(attn, mcol, scol);

    outl_kernel<<<B * H * 4, blk, 0, stream>>>(attn, fusion_r, mrow, srow, x_l, beta, out_l);
    outr_kernel<<<B * H * 4, blk, 0, stream>>>(attn, fusion_l, mcol, scol, x_r, gamma, out_r);
}

// Round 2
// 688.851 us; speedup vs baseline: 2.8546x; 2.8546x over previous
//
#include <hip/hip_runtime.h>
#include <hip/hip_bf16.h>

using bf16 = __hip_bfloat16;
typedef __attribute__((ext_vector_type(8))) short bf16x8;
typedef __attribute__((ext_vector_type(4))) float f32x4;

#define DEVI __device__ __forceinline__

constexpr int B = 4, C = 128, C2 = 256, H = 96, W = 256;
constexpr int HW = H * W;            // 24576
constexpr int NPIX = B * HW;         // 98304
constexpr int BH = B * H;            // 384
constexpr float SCALE = 0.08838834764831845f; // 128^-0.5
constexpr float LN_EPS = 1e-5f;

DEVI float lo16(unsigned u) { return __builtin_bit_cast(float, u << 16); }
DEVI float hi16(unsigned u) { return __builtin_bit_cast(float, u & 0xffff0000u); }
DEVI float bfu2f(unsigned short u) { return __builtin_bit_cast(float, (unsigned)u << 16); }
DEVI unsigned short f2bu(float v) {
    bf16 b = __float2bfloat16(v);
    return __builtin_bit_cast(unsigned short, b);
}
DEVI unsigned packbf2(float a, float b) {
    return (unsigned)f2bu(a) | ((unsigned)f2bu(b) << 16);
}

// ---------------------------------------------------------------------------
// T0: NCHW fp32 -> NHWC bf16 transpose/convert.  [B,C,HW] -> [NPIX, C]
// ---------------------------------------------------------------------------
__global__ __launch_bounds__(256) void transpose_kernel(
    const float* __restrict__ x, unsigned short* __restrict__ xT)
{
    __shared__ unsigned short ts[64][132];   // pad 132: 8B-aligned rows, low conflicts
    const int t = threadIdx.x;
    const int b = blockIdx.x / (HW / 64);
    const int hw0 = (blockIdx.x % (HW / 64)) * 64;
#pragma unroll
    for (int i = 0; i < 8; ++i) {
        int idx = t + i * 256;           // 2048 float4-tasks: 128c x 16 quads
        int c = idx >> 4;
        int px = (idx & 15) * 4;
        float4 v = *reinterpret_cast<const float4*>(&x[((size_t)b * C + c) * HW + hw0 + px]);
        ts[px + 0][c] = f2bu(v.x);
        ts[px + 1][c] = f2bu(v.y);
        ts[px + 2][c] = f2bu(v.z);
        ts[px + 3][c] = f2bu(v.w);
    }
    __syncthreads();
#pragma unroll
    for (int i = 0; i < 8; ++i) {
        int idx = t + i * 256;           // 2048 ushort4-tasks: 64px x 32 quads
        int px = idx >> 5;
        int c4 = (idx & 31) * 4;
        ushort4 v = *reinterpret_cast<const ushort4*>(&ts[px][c4]);
        *reinterpret_cast<ushort4*>(&xT[(size_t)(b * HW + hw0 + px) * C + c4]) = v;
    }
}

// ---------------------------------------------------------------------------
// K1: conv1x1 as MFMA GEMM.  y[px][oc] = sum_c xT[px][c] * Wm[oc][c]
// Block: 256 thr = 4 waves (2px x 2oc), tile 128px x 128oc. Grid 768 x 2.
// ---------------------------------------------------------------------------
__global__ __launch_bounds__(256) void conv1x1_mfma_kernel(
    const unsigned short* __restrict__ xT,  // [NPIX][C] bf16 bits
    const float* __restrict__ Wm,           // [C2][C] fp32
    unsigned short* __restrict__ y)         // [NPIX][C2] bf16 bits
{
    const int t = threadIdx.x;
    const int lane = t & 63, wid = t >> 6;
    const int wr = wid >> 1, wc = wid & 1;
    const int l15 = lane & 15, l4 = lane >> 4;
    const int pxb = blockIdx.x % 768;
    const int ocb = blockIdx.x / 768;

    const int px_base = pxb * 128 + wr * 64 + l15;
    const int oc_base = ocb * 128 + wc * 64 + l15;

    f32x4 acc[4][4] = {};
    for (int kk = 0; kk < 4; ++kk) {
        const int k0 = kk * 32 + l4 * 8;
        bf16x8 a[4], bb[4];
#pragma unroll
        for (int mt = 0; mt < 4; ++mt)
            a[mt] = *reinterpret_cast<const bf16x8*>(&xT[(size_t)(px_base + mt * 16) * C + k0]);
#pragma unroll
        for (int nt = 0; nt < 4; ++nt) {
            const float* wp = Wm + (size_t)(oc_base + nt * 16) * C + k0;
            float4 w0 = *reinterpret_cast<const float4*>(wp);
            float4 w1 = *reinterpret_cast<const float4*>(wp + 4);
            bf16x8 bv;
            bv[0] = (short)f2bu(w0.x); bv[1] = (short)f2bu(w0.y);
            bv[2] = (short)f2bu(w0.z); bv[3] = (short)f2bu(w0.w);
            bv[4] = (short)f2bu(w1.x); bv[5] = (short)f2bu(w1.y);
            bv[6] = (short)f2bu(w1.z); bv[7] = (short)f2bu(w1.w);
            bb[nt] = bv;
        }
#pragma unroll
        for (int mt = 0; mt < 4; ++mt)
#pragma unroll
            for (int nt = 0; nt < 4; ++nt)
                acc[mt][nt] = __builtin_amdgcn_mfma_f32_16x16x32_bf16(a[mt], bb[nt], acc[mt][nt], 0, 0, 0);
    }
#pragma unroll
    for (int mt = 0; mt < 4; ++mt)
#pragma unroll
        for (int nt = 0; nt < 4; ++nt) {
            const int oc = ocb * 128 + wc * 64 + nt * 16 + l15;
#pragma unroll
            for (int r = 0; r < 4; ++r) {
                const int px = pxb * 128 + wr * 64 + mt * 16 + l4 * 4 + r;
                y[(size_t)px * C2 + oc] = f2bu(acc[mt][nt][r]);
            }
        }
}

// ---------------------------------------------------------------------------
// K2: depthwise 3x3 on NHWC bf16. Thread: 8 channels x 8 pixels, weights in regs.
// Grid: BH * (W/64) blocks.
// ---------------------------------------------------------------------------
__global__ __launch_bounds__(256) void dwconv_kernel(
    const unsigned short* __restrict__ y,   // [NPIX][C2]
    const float* __restrict__ dwk,          // [C2][9]
    unsigned short* __restrict__ out)       // [NPIX][C2]
{
    const int t = threadIdx.x;
    const int wt = blockIdx.x & 3;
    const int bh = blockIdx.x >> 2;
    const int h = bh % H;
    const int ch8 = t & 31, wi = t >> 5;
    const int c0 = ch8 * 8;
    float wk[8][9];
#pragma unroll
    for (int j = 0; j < 8; ++j)
#pragma unroll
        for (int tap = 0; tap < 9; ++tap)
            wk[j][tap] = dwk[(c0 + j) * 9 + tap];
    const int wbase = wt * 64 + wi * 8;
    for (int i = 0; i < 8; ++i) {
        const int w = wbase + i;
        float acc[8] = {};
#pragma unroll
        for (int dh = 0; dh < 3; ++dh) {
            const int hh = h + dh - 1;
            if ((unsigned)hh >= (unsigned)H) continue;
#pragma unroll
            for (int dwi = 0; dwi < 3; ++dwi) {
                const int ww = w + dwi - 1;
                if ((unsigned)ww >= (unsigned)W) continue;
                const uint4 u = *reinterpret_cast<const uint4*>(
                    &y[((size_t)(bh + dh - 1) * W + ww) * C2 + c0]);
                const unsigned arr[4] = {u.x, u.y, u.z, u.w};
#pragma unroll
                for (int k = 0; k < 4; ++k) {
                    acc[k * 2]     = fmaf(lo16(arr[k]), wk[k * 2][dh * 3 + dwi], acc[k * 2]);
                    acc[k * 2 + 1] = fmaf(hi16(arr[k]), wk[k * 2 + 1][dh * 3 + dwi], acc[k * 2 + 1]);
                }
            }
        }
        uint4 o;
        o.x = packbf2(acc[0], acc[1]); o.y = packbf2(acc[2], acc[3]);
        o.z = packbf2(acc[4], acc[5]); o.w = packbf2(acc[6], acc[7]);
        *reinterpret_cast<uint4*>(&out[((size_t)bh * W + w) * C2 + c0]) = o;
    }
}

// ---------------------------------------------------------------------------
// K3: LayerNorm over C (mid = channels [C,2C) of NHWC fusion) + MFMA conv1x1 Q.
// Block: 256 thr, 64 px.  LDS: XOR-swizzled bf16 tile (G4 fix for stride-256B).
// ---------------------------------------------------------------------------
__global__ __launch_bounds__(256) void lnq_kernel(
    const unsigned short* __restrict__ fusion, // [NPIX][C2]
    const float* __restrict__ lnw, const float* __restrict__ lnb,
    const float* __restrict__ Wq,              // [C][C]
    const float* __restrict__ bq,              // [C]
    unsigned short* __restrict__ q)            // [NPIX][C]
{
    __shared__ float lnwb[256];
    __shared__ unsigned char msb[64 * 256];    // swizzled bf16 [64px][128c]
    const int t = threadIdx.x;
    const int px0 = blockIdx.x * 64;
    lnwb[t] = (t < 128) ? lnw[t] : lnb[t - 128];

    const int px = t >> 2, qq = t & 3;
    const size_t pbase = (size_t)(px0 + px) * C2 + C + qq * 32;
    uint4 raw[4];
#pragma unroll
    for (int u = 0; u < 4; ++u)
        raw[u] = *reinterpret_cast<const uint4*>(&fusion[pbase + u * 8]);
    float s1 = 0.f, s2 = 0.f;
#pragma unroll
    for (int u = 0; u < 4; ++u) {
        const unsigned arr[4] = {raw[u].x, raw[u].y, raw[u].z, raw[u].w};
#pragma unroll
        for (int k = 0; k < 4; ++k) {
            float v0 = lo16(arr[k]), v1 = hi16(arr[k]);
            s1 += v0 + v1; s2 += v0 * v0 + v1 * v1;
        }
    }
    s1 += __shfl_xor(s1, 1); s2 += __shfl_xor(s2, 1);
    s1 += __shfl_xor(s1, 2); s2 += __shfl_xor(s2, 2);
    const float mu = s1 * (1.f / C);
    const float rs = rsqrtf(s2 * (1.f / C) - mu * mu + LN_EPS);
    __syncthreads();   // lnwb ready
#pragma unroll
    for (int u = 0; u < 4; ++u) {
        const unsigned arr[4] = {raw[u].x, raw[u].y, raw[u].z, raw[u].w};
        float nv[8];
#pragma unroll
        for (int k = 0; k < 4; ++k) {
            int c = qq * 32 + u * 8 + k * 2;
            nv[k * 2]     = (lo16(arr[k]) - mu) * rs * lnwb[c] + lnwb[128 + c];
            nv[k * 2 + 1] = (hi16(arr[k]) - mu) * rs * lnwb[c + 1] + lnwb[128 + c + 1];
        }
        uint4 wv;
        wv.x = packbf2(nv[0], nv[1]); wv.y = packbf2(nv[2], nv[3]);
        wv.z = packbf2(nv[4], nv[5]); wv.w = packbf2(nv[6], nv[7]);
        unsigned addr = (unsigned)(px * 256 + qq * 64 + u * 16) ^ (unsigned)((px & 7) << 4);
        *reinterpret_cast<uint4*>(msb + addr) = wv;
    }
    __syncthreads();

    const int lane = t & 63, wid = t >> 6;
    const int l15 = lane & 15, l4 = lane >> 4;
    f32x4 acc[8] = {};
    for (int kk = 0; kk < 4; ++kk) {
        const int k0 = kk * 32 + l4 * 8;
        const int pxl = wid * 16 + l15;
        unsigned aaddr = (unsigned)(pxl * 256 + k0 * 2) ^ (unsigned)((pxl & 7) << 4);
        bf16x8 a = *reinterpret_cast<const bf16x8*>(msb + aaddr);
#pragma unroll
        for (int nt = 0; nt < 8; ++nt) {
            const float* wp = Wq + (size_t)(nt * 16 + l15) * C + k0;
            float4 w0 = *reinterpret_cast<const float4*>(wp);
            float4 w1 = *reinterpret_cast<const float4*>(wp + 4);
            bf16x8 bv;
            bv[0] = (short)f2bu(w0.x); bv[1] = (short)f2bu(w0.y);
            bv[2] = (short)f2bu(w0.z); bv[3] = (short)f2bu(w0.w);
            bv[4] = (short)f2bu(w1.x); bv[5] = (short)f2bu(w1.y);
            bv[6] = (short)f2bu(w1.z); bv[7] = (short)f2bu(w1.w);
            acc[nt] = __builtin_amdgcn_mfma_f32_16x16x32_bf16(a, bv, acc[nt], 0, 0, 0);
        }
    }
#pragma unroll
    for (int nt = 0; nt < 8; ++nt) {
        const int oc = nt * 16 + l15;
        const float bias = bq[oc];
#pragma unroll
        for (int r = 0; r < 4; ++r) {
            const int pxr = px0 + wid * 16 + l4 * 4 + r;
            q[(size_t)pxr * C + oc] = f2bu(acc[nt][r] + bias);
        }
    }
}

// ---------------------------------------------------------------------------
// K4: attn[bh][w][v] = SCALE * sum_c Ql[bh*W+w][c] * Qr[bh*W+v][c]  (MFMA)
// Block tile 64w x 64v; waves split w. Grid: BH*16.
// ---------------------------------------------------------------------------
__global__ __launch_bounds__(256) void attn_mfma_kernel(
    const unsigned short* __restrict__ ql, const unsigned short* __restrict__ qr,
    float* __restrict__ attn)   // [BH][W][W]
{
    const int t = threadIdx.x;
    const int lane = t & 63, wid = t >> 6;
    const int l15 = lane & 15, l4 = lane >> 4;
    const int bh = blockIdx.x >> 4;
    const int tile = blockIdx.x & 15;
    const int w0 = (tile >> 2) * 64, v0 = (tile & 3) * 64;
    const size_t pbh = (size_t)bh * W;

    f32x4 acc[4] = {};
    const int wrow = w0 + wid * 16 + l15;
    for (int kk = 0; kk < 4; ++kk) {
        const int k0 = kk * 32 + l4 * 8;
        bf16x8 a = *reinterpret_cast<const bf16x8*>(&ql[(pbh + wrow) * C + k0]);
#pragma unroll
        for (int nt = 0; nt < 4; ++nt) {
            bf16x8 bv = *reinterpret_cast<const bf16x8*>(&qr[(pbh + v0 + nt * 16 + l15) * C + k0]);
            acc[nt] = __builtin_amdgcn_mfma_f32_16x16x32_bf16(a, bv, acc[nt], 0, 0, 0);
        }
    }
#pragma unroll
    for (int nt = 0; nt < 4; ++nt)
#pragma unroll
        for (int r = 0; r < 4; ++r) {
            const int w = w0 + wid * 16 + l4 * 4 + r;
            attn[((size_t)bh * W + w) * W + v0 + nt * 16 + l15] = acc[nt][r] * SCALE;
        }
}

// ---------------------------------------------------------------------------
// K5a: row softmax stats, one wave per row.
// ---------------------------------------------------------------------------
__global__ __launch_bounds__(256) void rowstats_kernel(
    const float* __restrict__ attn, float* __restrict__ mrow, float* __restrict__ srow)
{
    const int gw = blockIdx.x * 4 + (threadIdx.x >> 6);
    const int lane = threadIdx.x & 63;
    const float* row = attn + (size_t)gw * W;
    float a0 = row[lane], a1 = row[lane + 64], a2 = row[lane + 128], a3 = row[lane + 192];
    float m = fmaxf(fmaxf(a0, a1), fmaxf(a2, a3));
#pragma unroll
    for (int off = 32; off; off >>= 1) m = fmaxf(m, __shfl_xor(m, off));
    float s = __expf(a0 - m) + __expf(a1 - m) + __expf(a2 - m) + __expf(a3 - m);
#pragma unroll
    for (int off = 32; off; off >>= 1) s += __shfl_xor(s, off);
    if (lane == 0) { mrow[gw] = m; srow[gw] = s; }
}

// ---------------------------------------------------------------------------
// K5b: col softmax stats, split-K (4 parts of 64 w) + combine.
// ---------------------------------------------------------------------------
__global__ __launch_bounds__(256) void colstats_part_kernel(
    const float* __restrict__ attn, float* __restrict__ pm, float* __restrict__ ps)
{
    const int bh = blockIdx.x >> 2, part = blockIdx.x & 3;
    const int v = threadIdx.x;
    const float* base = attn + (size_t)bh * W * W + (size_t)part * 64 * W + v;
    float m = -1e30f, s = 0.f;
    for (int w = 0; w < 64; ++w) {
        float a = base[w * W];
        float nm = fmaxf(m, a);
        s = s * __expf(m - nm) + __expf(a - nm);
        m = nm;
    }
    pm[((size_t)part * BH + bh) * W + v] = m;
    ps[((size_t)part * BH + bh) * W + v] = s;
}

__global__ __launch_bounds__(256) void colstats_comb_kernel(
    const float* __restrict__ pm, const float* __restrict__ ps,
    float* __restrict__ mcol, float* __restrict__ scol)
{
    const int bh = blockIdx.x;
    const int v = threadIdx.x;
    float mv[4], sv[4];
    float m = -1e30f;
#pragma unroll
    for (int p = 0; p < 4; ++p) {
        mv[p] = pm[((size_t)p * BH + bh) * W + v];
        sv[p] = ps[((size_t)p * BH + bh) * W + v];
        m = fmaxf(m, mv[p]);
    }
    float s = 0.f;
#pragma unroll
    for (int p = 0; p < 4; ++p) s += sv[p] * __expf(mv[p] - m);
    mcol[(size_t)bh * W + v] = m;
    scol[(size_t)bh * W + v] = s;
}

// ---------------------------------------------------------------------------
// K6: out_l = x_l + beta * softmax_row(attn) @ V_r    (V from NHWC fusion_r)
// ---------------------------------------------------------------------------
__global__ __launch_bounds__(256) void outl_kernel(
    const float* __restrict__ attn,
    const unsigned short* __restrict__ fusion_r,
    const float* __restrict__ mrow, const float* __restrict__ srow,
    const float* __restrict__ xl, const float* __restrict__ beta,
    float* __restrict__ outl)
{
    __shared__ float Vls[64][C];      // [v][c]
    __shared__ float Pls[64][65];     // [w][v]
    const int t = threadIdx.x;
    const int bh = blockIdx.x >> 2;
    const int w0 = (blockIdx.x & 3) * 64;
    const int b = bh / H, h = bh % H;
    const int wq = t & 15, cq = t >> 4;
    float acc[8][4] = {};

    for (int v0 = 0; v0 < W; v0 += 64) {
        __syncthreads();
        for (int idx = t; idx < 64 * C; idx += 256) {
            const int c = idx & 127, u = idx >> 7;
            Vls[u][c] = bfu2f(fusion_r[((size_t)bh * W + v0 + u) * C2 + c]);
        }
        for (int idx = t; idx < 64 * 64; idx += 256) {
            const int wl = idx >> 6, u = idx & 63;
            const float a = attn[((size_t)bh * W + w0 + wl) * W + v0 + u];
            Pls[wl][u] = __expf(a - mrow[(size_t)bh * W + w0 + wl]);
        }
        __syncthreads();
        for (int v = 0; v < 64; ++v) {
            float bb[4];
#pragma unroll
            for (int j = 0; j < 4; ++j) bb[j] = Pls[wq * 4 + j][v];
#pragma unroll
            for (int i = 0; i < 8; ++i) {
                const float av = Vls[v][cq * 8 + i];
#pragma unroll
                for (int j = 0; j < 4; ++j)
                    acc[i][j] = fmaf(av, bb[j], acc[i][j]);
            }
        }
    }
#pragma unroll
    for (int i = 0; i < 8; ++i) {
        const int c = cq * 8 + i;
        const float bt = beta[c];
#pragma unroll
        for (int j = 0; j < 4; ++j) {
            const int w = w0 + wq * 4 + j;
            const float r = acc[i][j] / srow[(size_t)bh * W + w];
            const size_t o = (size_t)(b * C + c) * HW + h * W + w;
            outl[o] = xl[o] + r * bt;
        }
    }
}

// ---------------------------------------------------------------------------
// K7: out_r = x_r + gamma * softmax_col(attn)^T @ V_l
// ---------------------------------------------------------------------------
__global__ __launch_bounds__(256) void outr_kernel(
    const float* __restrict__ attn,
    const unsigned short* __restrict__ fusion_l,
    const float* __restrict__ mcol, const float* __restrict__ scol,
    const float* __restrict__ xr, const float* __restrict__ gamma,
    float* __restrict__ outr)
{
    __shared__ float Vls[64][C];      // [w][c]
    __shared__ float Pls[64][68];     // [w][v], padded for float4
    const int t = threadIdx.x;
    const int bh = blockIdx.x >> 2;
    const int v0 = (blockIdx.x & 3) * 64;
    const int b = bh / H, h = bh % H;
    const int vq = t & 15, cq = t >> 4;
    float acc[8][4] = {};

    for (int w0 = 0; w0 < W; w0 += 64) {
        __syncthreads();
        for (int idx = t; idx < 64 * C; idx += 256) {
            const int c = idx & 127, u = idx >> 7;
            Vls[u][c] = bfu2f(fusion_l[((size_t)bh * W + w0 + u) * C2 + c]);
        }
        for (int idx = t; idx < 64 * 64; idx += 256) {
            const int wl = idx >> 6, u = idx & 63;
            const float a = attn[((size_t)bh * W + w0 + wl) * W + v0 + u];
            Pls[wl][u] = __expf(a - mcol[(size_t)bh * W + v0 + u]);
        }
        __syncthreads();
        for (int w = 0; w < 64; ++w) {
            const float4 bv = *reinterpret_cast<const float4*>(&Pls[w][vq * 4]);
            const float bb[4] = {bv.x, bv.y, bv.z, bv.w};
#pragma unroll
            for (int i = 0; i < 8; ++i) {
                const float av = Vls[w][cq * 8 + i];
#pragma unroll
                for (int j = 0; j < 4; ++j)
                    acc[i][j] = fmaf(av, bb[j], acc[i][j]);
            }
        }
    }
#pragma unroll
    for (int i = 0; i < 8; ++i) {
        const int c = cq * 8 + i;
        const float g = gamma[c];
#pragma unroll
        for (int j = 0; j < 4; ++j) {
            const int v = v0 + vq * 4 + j;
            const float r = acc[i][j] / scol[(size_t)bh * W + v];
            const size_t o = (size_t)(b * C + c) * HW + h * W + v;
            outr[o] = xr[o] + r * g;
        }
    }
}

// ---------------------------------------------------------------------------
extern "C" void kernel_launch(void* const* d_in, const int* in_sizes, int n_in,
                              void* d_out, int out_size, void* d_ws, size_t ws_size,
                              hipStream_t stream) {
    (void)in_sizes; (void)n_in; (void)out_size; (void)ws_size;
    const float* x_l   = (const float*)d_in[0];
    const float* x_r   = (const float*)d_in[1];
    const float* Wl_m  = (const float*)d_in[2];
    const float* Wr_m  = (const float*)d_in[3];
    const float* dw_l  = (const float*)d_in[4];
    const float* dw_r  = (const float*)d_in[5];
    const float* lnl_w = (const float*)d_in[6];
    const float* lnl_b = (const float*)d_in[7];
    const float* lnr_w = (const float*)d_in[8];
    const float* lnr_b = (const float*)d_in[9];
    const float* Wq_l  = (const float*)d_in[10];
    const float* bq_l  = (const float*)d_in[11];
    const float* Wq_r  = (const float*)d_in[12];
    const float* bq_r  = (const float*)d_in[13];
    const float* beta  = (const float*)d_in[14];
    const float* gamma = (const float*)d_in[15];

    char* ws = (char*)d_ws;
    unsigned short* fusion_l = (unsigned short*)(ws + 0);            // 50,331,648
    unsigned short* fusion_r = (unsigned short*)(ws + 50331648);     // 50,331,648
    unsigned short* Q_l      = (unsigned short*)(ws + 100663296);    // 25,165,824
    unsigned short* Q_r      = (unsigned short*)(ws + 125829120);    // 25,165,824
    float*          attn     = (float*)(ws + 150994944);             // 100,663,296
    // aliases inside attn region (dead before attn is written):
    unsigned short* xT_l     = (unsigned short*)(ws + 150994944);    // 25,165,824
    unsigned short* xT_r     = (unsigned short*)(ws + 176160768);    // 25,165,824
    unsigned short* ymid     = (unsigned short*)(ws + 201326592);    // 50,331,648
    float* mrow = (float*)(ws + 251658240);
    float* srow = (float*)(ws + 252051456);
    float* mcol = (float*)(ws + 252444672);
    float* scol = (float*)(ws + 252837888);
    // partial col-stats alias the (dead-after-attn) Q_l region:
    float* pm = (float*)(ws + 100663296);
    float* ps = (float*)(ws + 102236160);

    float* out_l = (float*)d_out;
    float* out_r = out_l + (size_t)B * C * HW;

    const dim3 blk(256);

    transpose_kernel<<<NPIX / 64, blk, 0, stream>>>(x_l, xT_l);
    transpose_kernel<<<NPIX / 64, blk, 0, stream>>>(x_r, xT_r);

    conv1x1_mfma_kernel<<<1536, blk, 0, stream>>>(xT_l, Wl_m, ymid);
    dwconv_kernel<<<BH * 4, blk, 0, stream>>>(ymid, dw_l, fusion_l);
    conv1x1_mfma_kernel<<<1536, blk, 0, stream>>>(xT_r, Wr_m, ymid);
    dwconv_kernel<<<BH * 4, blk, 0, stream>>>(ymid, dw_r, fusion_r);

    lnq_kernel<<<NPIX / 64, blk, 0, stream>>>(fusion_l, lnl_w, lnl_b, Wq_l, bq_l, Q_l);
    lnq_kernel<<<NPIX / 64, blk, 0, stream>>>(fusion_r, lnr_w, lnr_b, Wq_r, bq_r, Q_r);

    attn_mfma_kernel<<<BH * 16, blk, 0, stream>>>(Q_l, Q_r, attn);

    rowstats_kernel<<<NPIX / 4, blk, 0, stream>>>(attn, mrow, srow);
    colstats_part_kernel<<<BH * 4, blk, 0, stream>>>(attn, pm, ps);
    colstats_comb_kernel<<<BH, blk, 0, stream>>>(pm, ps, mcol, scol);

    outl_kernel<<<BH * 4, blk, 0, stream>>>(attn, fusion_r, mrow, srow, x_l, beta, out_l);
    outr_kernel<<<BH * 4, blk, 0, stream>>>(attn, fusion_l, mcol, scol, x_r, gamma, out_r);
}

// Round 3
// 593.353 us; speedup vs baseline: 3.3141x; 1.1609x over previous
//
#include <hip/hip_runtime.h>
#include <hip/hip_bf16.h>

using bf16 = __hip_bfloat16;
typedef __attribute__((ext_vector_type(8))) short bf16x8;
typedef __attribute__((ext_vector_type(4))) float f32x4;

#define DEVI __device__ __forceinline__

constexpr int B = 4, C = 128, C2 = 256, H = 96, W = 256;
constexpr int HW = H * W;            // 24576
constexpr int NPIX = B * HW;         // 98304
constexpr int BH = B * H;            // 384
constexpr float SCALE = 0.08838834764831845f; // 128^-0.5
constexpr float LN_EPS = 1e-5f;

DEVI float lo16(unsigned u) { return __builtin_bit_cast(float, u << 16); }
DEVI float hi16(unsigned u) { return __builtin_bit_cast(float, u & 0xffff0000u); }
DEVI float bfu2f(unsigned short u) { return __builtin_bit_cast(float, (unsigned)u << 16); }
DEVI unsigned short f2bu(float v) {
    bf16 b = __float2bfloat16(v);
    return __builtin_bit_cast(unsigned short, b);
}
DEVI unsigned packbf2(float a, float b) {
    return (unsigned)f2bu(a) | ((unsigned)f2bu(b) << 16);
}

// ---------------------------------------------------------------------------
// T0: NCHW fp32 -> NHWC bf16 transpose/convert.  [B,C,HW] -> [NPIX, C]
// ---------------------------------------------------------------------------
__global__ __launch_bounds__(256) void transpose_kernel(
    const float* __restrict__ x, unsigned short* __restrict__ xT)
{
    __shared__ unsigned short ts[64][132];
    const int t = threadIdx.x;
    const int b = blockIdx.x / (HW / 64);
    const int hw0 = (blockIdx.x % (HW / 64)) * 64;
#pragma unroll
    for (int i = 0; i < 8; ++i) {
        int idx = t + i * 256;
        int c = idx >> 4;
        int px = (idx & 15) * 4;
        float4 v = *reinterpret_cast<const float4*>(&x[((size_t)b * C + c) * HW + hw0 + px]);
        ts[px + 0][c] = f2bu(v.x);
        ts[px + 1][c] = f2bu(v.y);
        ts[px + 2][c] = f2bu(v.z);
        ts[px + 3][c] = f2bu(v.w);
    }
    __syncthreads();
#pragma unroll
    for (int i = 0; i < 8; ++i) {
        int idx = t + i * 256;
        int px = idx >> 5;
        int c4 = (idx & 31) * 4;
        ushort4 v = *reinterpret_cast<const ushort4*>(&ts[px][c4]);
        *reinterpret_cast<ushort4*>(&xT[(size_t)(b * HW + hw0 + px) * C + c4]) = v;
    }
}

// ---------------------------------------------------------------------------
// K1: conv1x1 as MFMA GEMM.  y[px][oc] = sum_c xT[px][c] * Wm[oc][c]
// ---------------------------------------------------------------------------
__global__ __launch_bounds__(256) void conv1x1_mfma_kernel(
    const unsigned short* __restrict__ xT,  // [NPIX][C]
    const float* __restrict__ Wm,           // [C2][C]
    unsigned short* __restrict__ y)         // [NPIX][C2]
{
    const int t = threadIdx.x;
    const int lane = t & 63, wid = t >> 6;
    const int wr = wid >> 1, wc = wid & 1;
    const int l15 = lane & 15, l4 = lane >> 4;
    const int pxb = blockIdx.x % 768;
    const int ocb = blockIdx.x / 768;

    const int px_base = pxb * 128 + wr * 64 + l15;
    const int oc_base = ocb * 128 + wc * 64 + l15;

    f32x4 acc[4][4] = {};
    for (int kk = 0; kk < 4; ++kk) {
        const int k0 = kk * 32 + l4 * 8;
        bf16x8 a[4], bb[4];
#pragma unroll
        for (int mt = 0; mt < 4; ++mt)
            a[mt] = *reinterpret_cast<const bf16x8*>(&xT[(size_t)(px_base + mt * 16) * C + k0]);
#pragma unroll
        for (int nt = 0; nt < 4; ++nt) {
            const float* wp = Wm + (size_t)(oc_base + nt * 16) * C + k0;
            float4 w0 = *reinterpret_cast<const float4*>(wp);
            float4 w1 = *reinterpret_cast<const float4*>(wp + 4);
            bf16x8 bv;
            bv[0] = (short)f2bu(w0.x); bv[1] = (short)f2bu(w0.y);
            bv[2] = (short)f2bu(w0.z); bv[3] = (short)f2bu(w0.w);
            bv[4] = (short)f2bu(w1.x); bv[5] = (short)f2bu(w1.y);
            bv[6] = (short)f2bu(w1.z); bv[7] = (short)f2bu(w1.w);
            bb[nt] = bv;
        }
#pragma unroll
        for (int mt = 0; mt < 4; ++mt)
#pragma unroll
            for (int nt = 0; nt < 4; ++nt)
                acc[mt][nt] = __builtin_amdgcn_mfma_f32_16x16x32_bf16(a[mt], bb[nt], acc[mt][nt], 0, 0, 0);
    }
#pragma unroll
    for (int mt = 0; mt < 4; ++mt)
#pragma unroll
        for (int nt = 0; nt < 4; ++nt) {
            const int oc = ocb * 128 + wc * 64 + nt * 16 + l15;
#pragma unroll
            for (int r = 0; r < 4; ++r) {
                const int px = pxb * 128 + wr * 64 + mt * 16 + l4 * 4 + r;
                y[(size_t)px * C2 + oc] = f2bu(acc[mt][nt][r]);
            }
        }
}

// ---------------------------------------------------------------------------
// K2: depthwise 3x3 on NHWC bf16.
// ---------------------------------------------------------------------------
__global__ __launch_bounds__(256) void dwconv_kernel(
    const unsigned short* __restrict__ y,   // [NPIX][C2]
    const float* __restrict__ dwk,          // [C2][9]
    unsigned short* __restrict__ out)       // [NPIX][C2]
{
    const int t = threadIdx.x;
    const int wt = blockIdx.x & 3;
    const int bh = blockIdx.x >> 2;
    const int h = bh % H;
    const int ch8 = t & 31, wi = t >> 5;
    const int c0 = ch8 * 8;
    float wk[8][9];
#pragma unroll
    for (int j = 0; j < 8; ++j)
#pragma unroll
        for (int tap = 0; tap < 9; ++tap)
            wk[j][tap] = dwk[(c0 + j) * 9 + tap];
    const int wbase = wt * 64 + wi * 8;
    for (int i = 0; i < 8; ++i) {
        const int w = wbase + i;
        float acc[8] = {};
#pragma unroll
        for (int dh = 0; dh < 3; ++dh) {
            const int hh = h + dh - 1;
            if ((unsigned)hh >= (unsigned)H) continue;
#pragma unroll
            for (int dwi = 0; dwi < 3; ++dwi) {
                const int ww = w + dwi - 1;
                if ((unsigned)ww >= (unsigned)W) continue;
                const uint4 u = *reinterpret_cast<const uint4*>(
                    &y[((size_t)(bh + dh - 1) * W + ww) * C2 + c0]);
                const unsigned arr[4] = {u.x, u.y, u.z, u.w};
#pragma unroll
                for (int k = 0; k < 4; ++k) {
                    acc[k * 2]     = fmaf(lo16(arr[k]), wk[k * 2][dh * 3 + dwi], acc[k * 2]);
                    acc[k * 2 + 1] = fmaf(hi16(arr[k]), wk[k * 2 + 1][dh * 3 + dwi], acc[k * 2 + 1]);
                }
            }
        }
        uint4 o;
        o.x = packbf2(acc[0], acc[1]); o.y = packbf2(acc[2], acc[3]);
        o.z = packbf2(acc[4], acc[5]); o.w = packbf2(acc[6], acc[7]);
        *reinterpret_cast<uint4*>(&out[((size_t)bh * W + w) * C2 + c0]) = o;
    }
}

// ---------------------------------------------------------------------------
// K3: LayerNorm over C + MFMA conv1x1 Q.
// ---------------------------------------------------------------------------
__global__ __launch_bounds__(256) void lnq_kernel(
    const unsigned short* __restrict__ fusion, // [NPIX][C2]
    const float* __restrict__ lnw, const float* __restrict__ lnb,
    const float* __restrict__ Wq,              // [C][C]
    const float* __restrict__ bq,              // [C]
    unsigned short* __restrict__ q)            // [NPIX][C]
{
    __shared__ float lnwb[256];
    __shared__ unsigned char msb[64 * 256];
    const int t = threadIdx.x;
    const int px0 = blockIdx.x * 64;
    lnwb[t] = (t < 128) ? lnw[t] : lnb[t - 128];

    const int px = t >> 2, qq = t & 3;
    const size_t pbase = (size_t)(px0 + px) * C2 + C + qq * 32;
    uint4 raw[4];
#pragma unroll
    for (int u = 0; u < 4; ++u)
        raw[u] = *reinterpret_cast<const uint4*>(&fusion[pbase + u * 8]);
    float s1 = 0.f, s2 = 0.f;
#pragma unroll
    for (int u = 0; u < 4; ++u) {
        const unsigned arr[4] = {raw[u].x, raw[u].y, raw[u].z, raw[u].w};
#pragma unroll
        for (int k = 0; k < 4; ++k) {
            float v0 = lo16(arr[k]), v1 = hi16(arr[k]);
            s1 += v0 + v1; s2 += v0 * v0 + v1 * v1;
        }
    }
    s1 += __shfl_xor(s1, 1); s2 += __shfl_xor(s2, 1);
    s1 += __shfl_xor(s1, 2); s2 += __shfl_xor(s2, 2);
    const float mu = s1 * (1.f / C);
    const float rs = rsqrtf(s2 * (1.f / C) - mu * mu + LN_EPS);
    __syncthreads();
#pragma unroll
    for (int u = 0; u < 4; ++u) {
        const unsigned arr[4] = {raw[u].x, raw[u].y, raw[u].z, raw[u].w};
        float nv[8];
#pragma unroll
        for (int k = 0; k < 4; ++k) {
            int c = qq * 32 + u * 8 + k * 2;
            nv[k * 2]     = (lo16(arr[k]) - mu) * rs * lnwb[c] + lnwb[128 + c];
            nv[k * 2 + 1] = (hi16(arr[k]) - mu) * rs * lnwb[c + 1] + lnwb[128 + c + 1];
        }
        uint4 wv;
        wv.x = packbf2(nv[0], nv[1]); wv.y = packbf2(nv[2], nv[3]);
        wv.z = packbf2(nv[4], nv[5]); wv.w = packbf2(nv[6], nv[7]);
        unsigned addr = (unsigned)(px * 256 + qq * 64 + u * 16) ^ (unsigned)((px & 7) << 4);
        *reinterpret_cast<uint4*>(msb + addr) = wv;
    }
    __syncthreads();

    const int lane = t & 63, wid = t >> 6;
    const int l15 = lane & 15, l4 = lane >> 4;
    f32x4 acc[8] = {};
    for (int kk = 0; kk < 4; ++kk) {
        const int k0 = kk * 32 + l4 * 8;
        const int pxl = wid * 16 + l15;
        unsigned aaddr = (unsigned)(pxl * 256 + k0 * 2) ^ (unsigned)((pxl & 7) << 4);
        bf16x8 a = *reinterpret_cast<const bf16x8*>(msb + aaddr);
#pragma unroll
        for (int nt = 0; nt < 8; ++nt) {
            const float* wp = Wq + (size_t)(nt * 16 + l15) * C + k0;
            float4 w0 = *reinterpret_cast<const float4*>(wp);
            float4 w1 = *reinterpret_cast<const float4*>(wp + 4);
            bf16x8 bv;
            bv[0] = (short)f2bu(w0.x); bv[1] = (short)f2bu(w0.y);
            bv[2] = (short)f2bu(w0.z); bv[3] = (short)f2bu(w0.w);
            bv[4] = (short)f2bu(w1.x); bv[5] = (short)f2bu(w1.y);
            bv[6] = (short)f2bu(w1.z); bv[7] = (short)f2bu(w1.w);
            acc[nt] = __builtin_amdgcn_mfma_f32_16x16x32_bf16(a, bv, acc[nt], 0, 0, 0);
        }
    }
#pragma unroll
    for (int nt = 0; nt < 8; ++nt) {
        const int oc = nt * 16 + l15;
        const float bias = bq[oc];
#pragma unroll
        for (int r = 0; r < 4; ++r) {
            const int pxr = px0 + wid * 16 + l4 * 4 + r;
            q[(size_t)pxr * C + oc] = f2bu(acc[nt][r] + bias);
        }
    }
}

// ---------------------------------------------------------------------------
// VT: per-(b,h) transpose of V channels: fusion[bh*W + v][c<128] -> VT[bh][c][v]
// Grid: BH * 2 (128-v chunks).
// ---------------------------------------------------------------------------
__global__ __launch_bounds__(256) void vtrans_kernel(
    const unsigned short* __restrict__ fusion,  // [NPIX][C2]
    unsigned short* __restrict__ VT)            // [BH][C][W]
{
    __shared__ unsigned short ts[128][136];
    const int t = threadIdx.x;
    const int bh = blockIdx.x >> 1;
    const int w0 = (blockIdx.x & 1) * 128;
#pragma unroll
    for (int i = 0; i < 8; ++i) {
        int idx = t + i * 256;              // 2048 tasks: 128 w x 16 c-octs
        int wl = idx >> 4, c8 = idx & 15;
        ushort4 v0 = *reinterpret_cast<const ushort4*>(
            &fusion[((size_t)bh * W + w0 + wl) * C2 + c8 * 8]);
        ushort4 v1 = *reinterpret_cast<const ushort4*>(
            &fusion[((size_t)bh * W + w0 + wl) * C2 + c8 * 8 + 4]);
        *reinterpret_cast<ushort4*>(&ts[wl][c8 * 8]) = v0;
        *reinterpret_cast<ushort4*>(&ts[wl][c8 * 8 + 4]) = v1;
    }
    __syncthreads();
#pragma unroll
    for (int i = 0; i < 8; ++i) {
        int idx = t + i * 256;              // 2048 tasks: 128 c x 16 w-octs
        int c = idx >> 4, w8 = idx & 15;
        unsigned short vals[8];
#pragma unroll
        for (int k = 0; k < 8; ++k) vals[k] = ts[w8 * 8 + k][c];
        *reinterpret_cast<ushort4*>(&VT[((size_t)bh * C + c) * W + w0 + w8 * 8]) =
            *reinterpret_cast<const ushort4*>(&vals[0]);
        *reinterpret_cast<ushort4*>(&VT[((size_t)bh * C + c) * W + w0 + w8 * 8 + 4]) =
            *reinterpret_cast<const ushort4*>(&vals[4]);
    }
}

// ---------------------------------------------------------------------------
// FUSED attention: out[b,c,h,w] = x[b,c,h,w] + coef[c] *
//        sum_v softmax_v( SCALE * sum_k Q[w,k] K[v,k] ) * VT[c,v]
// Grid: BH*4 blocks, 4 waves, each wave owns 16 q-rows. No barriers.
// ---------------------------------------------------------------------------
__global__ __launch_bounds__(256) void fused_attn_kernel(
    const unsigned short* __restrict__ Q,   // [NPIX][C]
    const unsigned short* __restrict__ K,   // [NPIX][C]
    const unsigned short* __restrict__ VT,  // [BH][C][W]
    const float* __restrict__ x,            // [B,C,H,W]
    const float* __restrict__ coef,         // [C]
    float* __restrict__ out)                // [B,C,H,W]
{
    __shared__ __align__(16) unsigned char smem[4 * 10240];
    const int t = threadIdx.x;
    const int lane = t & 63, wv = t >> 6;
    const int l15 = lane & 15, l4 = lane >> 4;
    const int bh = blockIdx.x >> 2;
    const int w0 = (blockIdx.x & 3) * 64 + wv * 16;   // this wave's 16 q-rows
    const int b = bh / H, h = bh % H;
    unsigned char* mybase = smem + wv * 10240;

    // ---- S = Q[w0..w0+15] @ K^T  (16 x 256), scaled ----
    f32x4 sacc[16];
#pragma unroll
    for (int nt = 0; nt < 16; ++nt) sacc[nt] = f32x4{0.f, 0.f, 0.f, 0.f};
    const size_t qrow = ((size_t)bh * W + w0 + l15) * C;
    const size_t kbase = (size_t)bh * W * C;
#pragma unroll
    for (int ks = 0; ks < 4; ++ks) {
        const int k0 = ks * 32 + l4 * 8;
        bf16x8 a = *reinterpret_cast<const bf16x8*>(&Q[qrow + k0]);
#pragma unroll
        for (int nt = 0; nt < 16; ++nt) {
            bf16x8 bv = *reinterpret_cast<const bf16x8*>(&K[kbase + (size_t)(nt * 16 + l15) * C + k0]);
            sacc[nt] = __builtin_amdgcn_mfma_f32_16x16x32_bf16(a, bv, sacc[nt], 0, 0, 0);
        }
    }

    // ---- row softmax, fully in-register ----
    // sacc[nt][r]: row (l4*4+r), col (nt*16+l15). Reduce over nt + l15 group.
    float m[4], sden[4];
#pragma unroll
    for (int r = 0; r < 4; ++r) {
        float mx = -1e30f;
#pragma unroll
        for (int nt = 0; nt < 16; ++nt) {
            sacc[nt][r] *= SCALE;
            mx = fmaxf(mx, sacc[nt][r]);
        }
#pragma unroll
        for (int off = 1; off <= 8; off <<= 1) mx = fmaxf(mx, __shfl_xor(mx, off));
        m[r] = mx;
        float s = 0.f;
#pragma unroll
        for (int nt = 0; nt < 16; ++nt) {
            float e = __expf(sacc[nt][r] - mx);
            sacc[nt][r] = e;
            s += e;
        }
#pragma unroll
        for (int off = 1; off <= 8; off <<= 1) s += __shfl_xor(s, off);
        sden[r] = 1.f / s;
    }

    // ---- write normalized P (bf16) to per-wave LDS, stride 264 ----
    unsigned short* pb = (unsigned short*)mybase;
#pragma unroll
    for (int nt = 0; nt < 16; ++nt)
#pragma unroll
        for (int r = 0; r < 4; ++r)
            pb[(l4 * 4 + r) * 264 + nt * 16 + l15] = f2bu(sacc[nt][r] * sden[r]);

    // ---- O = P @ V  (16 x 128) via MFMA; A from LDS, B from VT global ----
    f32x4 oacc[8];
#pragma unroll
    for (int nt = 0; nt < 8; ++nt) oacc[nt] = f32x4{0.f, 0.f, 0.f, 0.f};
    const size_t vtb = (size_t)bh * C * W;
#pragma unroll
    for (int ks = 0; ks < 8; ++ks) {
        bf16x8 a = *reinterpret_cast<const bf16x8*>(&pb[l15 * 264 + ks * 32 + l4 * 8]);
#pragma unroll
        for (int nt = 0; nt < 8; ++nt) {
            bf16x8 bv = *reinterpret_cast<const bf16x8*>(
                &VT[vtb + (size_t)(nt * 16 + l15) * W + ks * 32 + l4 * 8]);
            oacc[nt] = __builtin_amdgcn_mfma_f32_16x16x32_bf16(a, bv, oacc[nt], 0, 0, 0);
        }
    }

    // ---- epilogue: transpose via per-wave LDS (f32, stride 20), add residual ----
    float* eb = (float*)mybase;
#pragma unroll
    for (int nt = 0; nt < 8; ++nt)
#pragma unroll
        for (int r = 0; r < 4; ++r)
            eb[(nt * 16 + l15) * 20 + l4 * 4 + r] = oacc[nt][r];

#pragma unroll
    for (int half = 0; half < 2; ++half) {
        const int c = half * 64 + lane;
        const float cf = coef[c];
        const size_t g = (size_t)(b * C + c) * HW + (size_t)h * W + w0;
#pragma unroll
        for (int qd = 0; qd < 4; ++qd) {
            float4 f = *reinterpret_cast<const float4*>(&eb[c * 20 + qd * 4]);
            float4 xv = *reinterpret_cast<const float4*>(&x[g + qd * 4]);
            float4 o;
            o.x = xv.x + f.x * cf; o.y = xv.y + f.y * cf;
            o.z = xv.z + f.z * cf; o.w = xv.w + f.w * cf;
            *reinterpret_cast<float4*>(&out[g + qd * 4]) = o;
        }
    }
}

// ---------------------------------------------------------------------------
extern "C" void kernel_launch(void* const* d_in, const int* in_sizes, int n_in,
                              void* d_out, int out_size, void* d_ws, size_t ws_size,
                              hipStream_t stream) {
    (void)in_sizes; (void)n_in; (void)out_size; (void)ws_size;
    const float* x_l   = (const float*)d_in[0];
    const float* x_r   = (const float*)d_in[1];
    const float* Wl_m  = (const float*)d_in[2];
    const float* Wr_m  = (const float*)d_in[3];
    const float* dw_l  = (const float*)d_in[4];
    const float* dw_r  = (const float*)d_in[5];
    const float* lnl_w = (const float*)d_in[6];
    const float* lnl_b = (const float*)d_in[7];
    const float* lnr_w = (const float*)d_in[8];
    const float* lnr_b = (const float*)d_in[9];
    const float* Wq_l  = (const float*)d_in[10];
    const float* bq_l  = (const float*)d_in[11];
    const float* Wq_r  = (const float*)d_in[12];
    const float* bq_r  = (const float*)d_in[13];
    const float* beta  = (const float*)d_in[14];
    const float* gamma = (const float*)d_in[15];

    char* ws = (char*)d_ws;
    unsigned short* fusion_l = (unsigned short*)(ws + 0);            // 50,331,648
    unsigned short* fusion_r = (unsigned short*)(ws + 50331648);     // 50,331,648
    unsigned short* Q_l      = (unsigned short*)(ws + 100663296);    // 25,165,824
    unsigned short* Q_r      = (unsigned short*)(ws + 125829120);    // 25,165,824
    unsigned short* VT_l     = (unsigned short*)(ws + 150994944);    // 25,165,824
    unsigned short* VT_r     = (unsigned short*)(ws + 176160768);    // 25,165,824
    unsigned short* ymid     = (unsigned short*)(ws + 201326592);    // 50,331,648
    // xT buffers alias the VT region (dead once conv1x1 consumed them):
    unsigned short* xT_l     = VT_l;
    unsigned short* xT_r     = VT_r;

    float* out_l = (float*)d_out;
    float* out_r = out_l + (size_t)B * C * HW;

    const dim3 blk(256);

    transpose_kernel<<<NPIX / 64, blk, 0, stream>>>(x_l, xT_l);
    conv1x1_mfma_kernel<<<1536, blk, 0, stream>>>(xT_l, Wl_m, ymid);
    dwconv_kernel<<<BH * 4, blk, 0, stream>>>(ymid, dw_l, fusion_l);

    transpose_kernel<<<NPIX / 64, blk, 0, stream>>>(x_r, xT_r);
    conv1x1_mfma_kernel<<<1536, blk, 0, stream>>>(xT_r, Wr_m, ymid);
    dwconv_kernel<<<BH * 4, blk, 0, stream>>>(ymid, dw_r, fusion_r);

    // VT overwrites xT (both consumed by now)
    vtrans_kernel<<<BH * 2, blk, 0, stream>>>(fusion_l, VT_l);
    vtrans_kernel<<<BH * 2, blk, 0, stream>>>(fusion_r, VT_r);

    lnq_kernel<<<NPIX / 64, blk, 0, stream>>>(fusion_l, lnl_w, lnl_b, Wq_l, bq_l, Q_l);
    lnq_kernel<<<NPIX / 64, blk, 0, stream>>>(fusion_r, lnr_w, lnr_b, Wq_r, bq_r, Q_r);

    // out_l = x_l + beta * softmax_row(Ql Qr^T) @ V_r
    fused_attn_kernel<<<BH * 4, blk, 0, stream>>>(Q_l, Q_r, VT_r, x_l, beta, out_l);
    // out_r = x_r + gamma * softmax_row(Qr Ql^T) @ V_l
    fused_attn_kernel<<<BH * 4, blk, 0, stream>>>(Q_r, Q_l, VT_l, x_r, gamma, out_r);
}

// Round 4
// 454.188 us; speedup vs baseline: 4.3295x; 1.3064x over previous
//
#include <hip/hip_runtime.h>
#include <hip/hip_bf16.h>

using bf16 = __hip_bfloat16;
typedef __attribute__((ext_vector_type(8))) short bf16x8;
typedef __attribute__((ext_vector_type(4))) float f32x4;

#define DEVI __device__ __forceinline__

constexpr int B = 4, C = 128, C2 = 256, H = 96, W = 256;
constexpr int HW = H * W;            // 24576
constexpr int NPIX = B * HW;         // 98304
constexpr int BH = B * H;            // 384
constexpr float SCALE = 0.08838834764831845f; // 128^-0.5
constexpr float LN_EPS = 1e-5f;

DEVI float lo16(unsigned u) { return __builtin_bit_cast(float, u << 16); }
DEVI float hi16(unsigned u) { return __builtin_bit_cast(float, u & 0xffff0000u); }
DEVI float bfu2f(unsigned short u) { return __builtin_bit_cast(float, (unsigned)u << 16); }
DEVI unsigned short f2bu(float v) {
    bf16 b = __float2bfloat16(v);
    return __builtin_bit_cast(unsigned short, b);
}
DEVI unsigned packbf2(float a, float b) {
    return (unsigned)f2bu(a) | ((unsigned)f2bu(b) << 16);
}

// ---------------------------------------------------------------------------
// W0: convert the 4 weight matrices fp32 -> bf16 (one small kernel, 24 blocks)
// blocks 0-7: Wl (32768), 8-15: Wr (32768), 16-19: Wql (16384), 20-23: Wqr
// ---------------------------------------------------------------------------
__global__ __launch_bounds__(256) void wcvt_kernel(
    const float* __restrict__ w0, const float* __restrict__ w1,
    const float* __restrict__ w2, const float* __restrict__ w3,
    unsigned short* __restrict__ o0, unsigned short* __restrict__ o1,
    unsigned short* __restrict__ o2, unsigned short* __restrict__ o3)
{
    const int id = blockIdx.x, t = threadIdx.x;
    const float* src; unsigned short* dst; int base;
    if (id < 8)       { src = w0; dst = o0; base = id * 4096; }
    else if (id < 16) { src = w1; dst = o1; base = (id - 8) * 4096; }
    else if (id < 20) { src = w2; dst = o2; base = (id - 16) * 4096; }
    else              { src = w3; dst = o3; base = (id - 20) * 4096; }
#pragma unroll
    for (int u = 0; u < 4; ++u) {
        int i = base + t * 16 + u * 4;
        float4 v = *reinterpret_cast<const float4*>(&src[i]);
        ushort4 o;
        o.x = f2bu(v.x); o.y = f2bu(v.y); o.z = f2bu(v.z); o.w = f2bu(v.w);
        *reinterpret_cast<ushort4*>(&dst[i]) = o;
    }
}

// ---------------------------------------------------------------------------
// T0: NCHW fp32 -> NHWC bf16 transpose/convert.  [B,C,HW] -> [NPIX, C]
// ---------------------------------------------------------------------------
__global__ __launch_bounds__(256) void transpose_kernel(
    const float* __restrict__ x, unsigned short* __restrict__ xT)
{
    __shared__ unsigned short ts[64][132];
    const int t = threadIdx.x;
    const int b = blockIdx.x / (HW / 64);
    const int hw0 = (blockIdx.x % (HW / 64)) * 64;
#pragma unroll
    for (int i = 0; i < 8; ++i) {
        int idx = t + i * 256;
        int c = idx >> 4;
        int px = (idx & 15) * 4;
        float4 v = *reinterpret_cast<const float4*>(&x[((size_t)b * C + c) * HW + hw0 + px]);
        ts[px + 0][c] = f2bu(v.x);
        ts[px + 1][c] = f2bu(v.y);
        ts[px + 2][c] = f2bu(v.z);
        ts[px + 3][c] = f2bu(v.w);
    }
    __syncthreads();
#pragma unroll
    for (int i = 0; i < 8; ++i) {
        int idx = t + i * 256;
        int px = idx >> 5;
        int c4 = (idx & 31) * 4;
        ushort4 v = *reinterpret_cast<const ushort4*>(&ts[px][c4]);
        *reinterpret_cast<ushort4*>(&xT[(size_t)(b * HW + hw0 + px) * C + c4]) = v;
    }
}

// ---------------------------------------------------------------------------
// K1: conv1x1 as MFMA GEMM (bf16 weights).
// ---------------------------------------------------------------------------
__global__ __launch_bounds__(256) void conv1x1_mfma_kernel(
    const unsigned short* __restrict__ xT,  // [NPIX][C]
    const unsigned short* __restrict__ Wb,  // [C2][C] bf16
    unsigned short* __restrict__ y)         // [NPIX][C2]
{
    const int t = threadIdx.x;
    const int lane = t & 63, wid = t >> 6;
    const int wr = wid >> 1, wc = wid & 1;
    const int l15 = lane & 15, l4 = lane >> 4;
    const int pxb = blockIdx.x % 768;
    const int ocb = blockIdx.x / 768;

    const int px_base = pxb * 128 + wr * 64 + l15;
    const int oc_base = ocb * 128 + wc * 64 + l15;

    f32x4 acc[4][4] = {};
    for (int kk = 0; kk < 4; ++kk) {
        const int k0 = kk * 32 + l4 * 8;
        bf16x8 a[4], bb[4];
#pragma unroll
        for (int mt = 0; mt < 4; ++mt)
            a[mt] = *reinterpret_cast<const bf16x8*>(&xT[(size_t)(px_base + mt * 16) * C + k0]);
#pragma unroll
        for (int nt = 0; nt < 4; ++nt)
            bb[nt] = *reinterpret_cast<const bf16x8*>(&Wb[(size_t)(oc_base + nt * 16) * C + k0]);
#pragma unroll
        for (int mt = 0; mt < 4; ++mt)
#pragma unroll
            for (int nt = 0; nt < 4; ++nt)
                acc[mt][nt] = __builtin_amdgcn_mfma_f32_16x16x32_bf16(a[mt], bb[nt], acc[mt][nt], 0, 0, 0);
    }
#pragma unroll
    for (int mt = 0; mt < 4; ++mt)
#pragma unroll
        for (int nt = 0; nt < 4; ++nt) {
            const int oc = ocb * 128 + wc * 64 + nt * 16 + l15;
#pragma unroll
            for (int r = 0; r < 4; ++r) {
                const int px = pxb * 128 + wr * 64 + mt * 16 + l4 * 4 + r;
                y[(size_t)px * C2 + oc] = f2bu(acc[mt][nt][r]);
            }
        }
}

// ---------------------------------------------------------------------------
// K2: depthwise 3x3 on NHWC bf16.
// ---------------------------------------------------------------------------
__global__ __launch_bounds__(256) void dwconv_kernel(
    const unsigned short* __restrict__ y,   // [NPIX][C2]
    const float* __restrict__ dwk,          // [C2][9]
    unsigned short* __restrict__ out)       // [NPIX][C2]
{
    const int t = threadIdx.x;
    const int wt = blockIdx.x & 3;
    const int bh = blockIdx.x >> 2;
    const int h = bh % H;
    const int ch8 = t & 31, wi = t >> 5;
    const int c0 = ch8 * 8;
    float wk[8][9];
#pragma unroll
    for (int j = 0; j < 8; ++j)
#pragma unroll
        for (int tap = 0; tap < 9; ++tap)
            wk[j][tap] = dwk[(c0 + j) * 9 + tap];
    const int wbase = wt * 64 + wi * 8;
    for (int i = 0; i < 8; ++i) {
        const int w = wbase + i;
        float acc[8] = {};
#pragma unroll
        for (int dh = 0; dh < 3; ++dh) {
            const int hh = h + dh - 1;
            if ((unsigned)hh >= (unsigned)H) continue;
#pragma unroll
            for (int dwi = 0; dwi < 3; ++dwi) {
                const int ww = w + dwi - 1;
                if ((unsigned)ww >= (unsigned)W) continue;
                const uint4 u = *reinterpret_cast<const uint4*>(
                    &y[((size_t)(bh + dh - 1) * W + ww) * C2 + c0]);
                const unsigned arr[4] = {u.x, u.y, u.z, u.w};
#pragma unroll
                for (int k = 0; k < 4; ++k) {
                    acc[k * 2]     = fmaf(lo16(arr[k]), wk[k * 2][dh * 3 + dwi], acc[k * 2]);
                    acc[k * 2 + 1] = fmaf(hi16(arr[k]), wk[k * 2 + 1][dh * 3 + dwi], acc[k * 2 + 1]);
                }
            }
        }
        uint4 o;
        o.x = packbf2(acc[0], acc[1]); o.y = packbf2(acc[2], acc[3]);
        o.z = packbf2(acc[4], acc[5]); o.w = packbf2(acc[6], acc[7]);
        *reinterpret_cast<uint4*>(&out[((size_t)bh * W + w) * C2 + c0]) = o;
    }
}

// ---------------------------------------------------------------------------
// K3: LayerNorm over C + MFMA conv1x1 Q (bf16 weights).
// ---------------------------------------------------------------------------
__global__ __launch_bounds__(256) void lnq_kernel(
    const unsigned short* __restrict__ fusion, // [NPIX][C2]
    const float* __restrict__ lnw, const float* __restrict__ lnb,
    const unsigned short* __restrict__ Wqb,    // [C][C] bf16
    const float* __restrict__ bq,              // [C]
    unsigned short* __restrict__ q)            // [NPIX][C]
{
    __shared__ float lnwb[256];
    __shared__ unsigned char msb[64 * 256];
    const int t = threadIdx.x;
    const int px0 = blockIdx.x * 64;
    lnwb[t] = (t < 128) ? lnw[t] : lnb[t - 128];

    const int px = t >> 2, qq = t & 3;
    const size_t pbase = (size_t)(px0 + px) * C2 + C + qq * 32;
    uint4 raw[4];
#pragma unroll
    for (int u = 0; u < 4; ++u)
        raw[u] = *reinterpret_cast<const uint4*>(&fusion[pbase + u * 8]);
    float s1 = 0.f, s2 = 0.f;
#pragma unroll
    for (int u = 0; u < 4; ++u) {
        const unsigned arr[4] = {raw[u].x, raw[u].y, raw[u].z, raw[u].w};
#pragma unroll
        for (int k = 0; k < 4; ++k) {
            float v0 = lo16(arr[k]), v1 = hi16(arr[k]);
            s1 += v0 + v1; s2 += v0 * v0 + v1 * v1;
        }
    }
    s1 += __shfl_xor(s1, 1); s2 += __shfl_xor(s2, 1);
    s1 += __shfl_xor(s1, 2); s2 += __shfl_xor(s2, 2);
    const float mu = s1 * (1.f / C);
    const float rs = rsqrtf(s2 * (1.f / C) - mu * mu + LN_EPS);
    __syncthreads();
#pragma unroll
    for (int u = 0; u < 4; ++u) {
        const unsigned arr[4] = {raw[u].x, raw[u].y, raw[u].z, raw[u].w};
        float nv[8];
#pragma unroll
        for (int k = 0; k < 4; ++k) {
            int c = qq * 32 + u * 8 + k * 2;
            nv[k * 2]     = (lo16(arr[k]) - mu) * rs * lnwb[c] + lnwb[128 + c];
            nv[k * 2 + 1] = (hi16(arr[k]) - mu) * rs * lnwb[c + 1] + lnwb[128 + c + 1];
        }
        uint4 wv;
        wv.x = packbf2(nv[0], nv[1]); wv.y = packbf2(nv[2], nv[3]);
        wv.z = packbf2(nv[4], nv[5]); wv.w = packbf2(nv[6], nv[7]);
        unsigned addr = (unsigned)(px * 256 + qq * 64 + u * 16) ^ (unsigned)((px & 7) << 4);
        *reinterpret_cast<uint4*>(msb + addr) = wv;
    }
    __syncthreads();

    const int lane = t & 63, wid = t >> 6;
    const int l15 = lane & 15, l4 = lane >> 4;
    f32x4 acc[8] = {};
    for (int kk = 0; kk < 4; ++kk) {
        const int k0 = kk * 32 + l4 * 8;
        const int pxl = wid * 16 + l15;
        unsigned aaddr = (unsigned)(pxl * 256 + k0 * 2) ^ (unsigned)((pxl & 7) << 4);
        bf16x8 a = *reinterpret_cast<const bf16x8*>(msb + aaddr);
#pragma unroll
        for (int nt = 0; nt < 8; ++nt) {
            bf16x8 bv = *reinterpret_cast<const bf16x8*>(&Wqb[(size_t)(nt * 16 + l15) * C + k0]);
            acc[nt] = __builtin_amdgcn_mfma_f32_16x16x32_bf16(a, bv, acc[nt], 0, 0, 0);
        }
    }
#pragma unroll
    for (int nt = 0; nt < 8; ++nt) {
        const int oc = nt * 16 + l15;
        const float bias = bq[oc];
#pragma unroll
        for (int r = 0; r < 4; ++r) {
            const int pxr = px0 + wid * 16 + l4 * 4 + r;
            q[(size_t)pxr * C + oc] = f2bu(acc[nt][r] + bias);
        }
    }
}

// ---------------------------------------------------------------------------
// VT: per-(b,h) transpose of V channels: fusion[bh*W + v][c<128] -> VT[bh][c][v]
// ---------------------------------------------------------------------------
__global__ __launch_bounds__(256) void vtrans_kernel(
    const unsigned short* __restrict__ fusion,  // [NPIX][C2]
    unsigned short* __restrict__ VT)            // [BH][C][W]
{
    __shared__ unsigned short ts[128][136];
    const int t = threadIdx.x;
    const int bh = blockIdx.x >> 1;
    const int w0 = (blockIdx.x & 1) * 128;
#pragma unroll
    for (int i = 0; i < 8; ++i) {
        int idx = t + i * 256;
        int wl = idx >> 4, c8 = idx & 15;
        ushort4 v0 = *reinterpret_cast<const ushort4*>(
            &fusion[((size_t)bh * W + w0 + wl) * C2 + c8 * 8]);
        ushort4 v1 = *reinterpret_cast<const ushort4*>(
            &fusion[((size_t)bh * W + w0 + wl) * C2 + c8 * 8 + 4]);
        *reinterpret_cast<ushort4*>(&ts[wl][c8 * 8]) = v0;
        *reinterpret_cast<ushort4*>(&ts[wl][c8 * 8 + 4]) = v1;
    }
    __syncthreads();
#pragma unroll
    for (int i = 0; i < 8; ++i) {
        int idx = t + i * 256;
        int c = idx >> 4, w8 = idx & 15;
        unsigned short vals[8];
#pragma unroll
        for (int k = 0; k < 8; ++k) vals[k] = ts[w8 * 8 + k][c];
        *reinterpret_cast<ushort4*>(&VT[((size_t)bh * C + c) * W + w0 + w8 * 8]) =
            *reinterpret_cast<const ushort4*>(&vals[0]);
        *reinterpret_cast<ushort4*>(&VT[((size_t)bh * C + c) * W + w0 + w8 * 8 + 4]) =
            *reinterpret_cast<const ushort4*>(&vals[4]);
    }
}

// ---------------------------------------------------------------------------
// FUSED attention, 8-wave blocks, K staged in LDS (XOR-swizzled via
// pre-swizzled global source), P overlays K region after barrier.
// Grid: 768 (XCD-swizzled: 2 blocks of each bh on the same XCD).
// ---------------------------------------------------------------------------
__global__ __launch_bounds__(512, 4) void fused_attn_kernel(
    const unsigned short* __restrict__ Q,   // [NPIX][C]
    const unsigned short* __restrict__ K,   // [NPIX][C]
    const unsigned short* __restrict__ VT,  // [BH][C][W]
    const float* __restrict__ x,            // [B,C,H,W]
    const float* __restrict__ coef,         // [C]
    float* __restrict__ out)                // [B,C,H,W]
{
    __shared__ __align__(16) unsigned char lds[65536];
    const int t = threadIdx.x;
    const int lane = t & 63, wv = t >> 6;
    const int l15 = lane & 15, l4 = lane >> 4;

    // XCD swizzle: 768 blocks, 8 XCDs, 96 slots each; 2 consecutive slots = 1 bh
    const int bid = blockIdx.x;
    const int xcd = bid & 7, slot = bid >> 3;
    const int bh = xcd * 48 + (slot >> 1);
    const int hlf = slot & 1;
    const int b = bh / H, h = bh % H;
    const int w0w = hlf * 128 + wv * 16;   // this wave's first q-row

    // ---- Q fragments (issued before staging waits) ----
    const size_t qrow = ((size_t)bh * W + w0w + l15) * C;
    bf16x8 qa[4];
#pragma unroll
    for (int ks = 0; ks < 4; ++ks)
        qa[ks] = *reinterpret_cast<const bf16x8*>(&Q[qrow + ks * 32 + l4 * 8]);

    // ---- stage K [256][128]bf16 into LDS, XOR-swizzled via source ----
    {
        const char* kgb = (const char*)(K + (size_t)bh * W * C);
        const int rowl = lane >> 4;
        const int cb = (lane & 15) * 16;
#pragma unroll
        for (int i = 0; i < 8; ++i) {
            const int r0 = wv * 32 + i * 4;
            const int row = r0 + rowl;
            const char* src = kgb + row * 256 + (cb ^ ((row & 7) << 4));
            __builtin_amdgcn_global_load_lds(
                (const __attribute__((address_space(1))) void*)src,
                (__attribute__((address_space(3))) void*)(lds + r0 * 256), 16, 0, 0);
        }
    }
    __syncthreads();

    // ---- S = Q K^T : 16 q-rows x 256 v, from LDS ----
    f32x4 sacc[16];
#pragma unroll
    for (int nt = 0; nt < 16; ++nt) sacc[nt] = f32x4{0.f, 0.f, 0.f, 0.f};
#pragma unroll
    for (int ks = 0; ks < 4; ++ks) {
        const int bcol = ks * 64 + l4 * 16;
#pragma unroll
        for (int nt = 0; nt < 16; ++nt) {
            const int v = nt * 16 + l15;
            bf16x8 bv = *reinterpret_cast<const bf16x8*>(
                lds + v * 256 + (bcol ^ ((v & 7) << 4)));
            sacc[nt] = __builtin_amdgcn_mfma_f32_16x16x32_bf16(qa[ks], bv, sacc[nt], 0, 0, 0);
        }
    }

    // ---- row softmax fully in-register (rows = l4*4+r, cols over nt,l15) ----
    float sden[4];
#pragma unroll
    for (int r = 0; r < 4; ++r) {
        float mx = -1e30f;
#pragma unroll
        for (int nt = 0; nt < 16; ++nt) {
            sacc[nt][r] *= SCALE;
            mx = fmaxf(mx, sacc[nt][r]);
        }
#pragma unroll
        for (int off = 1; off <= 8; off <<= 1) mx = fmaxf(mx, __shfl_xor(mx, off));
        float s = 0.f;
#pragma unroll
        for (int nt = 0; nt < 16; ++nt) {
            float e = __expf(sacc[nt][r] - mx);
            sacc[nt][r] = e;
            s += e;
        }
#pragma unroll
        for (int off = 1; off <= 8; off <<= 1) s += __shfl_xor(s, off);
        sden[r] = 1.f / s;
    }

    __syncthreads();   // all waves done reading K; K region now reusable

    // ---- write normalized P (bf16) into this wave's 8KB slice, swizzled ----
    unsigned char* pb = lds + wv * 8192;
#pragma unroll
    for (int nt = 0; nt < 16; ++nt) {
        const int vc = nt * 16 + l15;
#pragma unroll
        for (int r = 0; r < 4; ++r) {
            const int wrow = l4 * 4 + r;
            *(unsigned short*)(pb + wrow * 512 + ((vc * 2) ^ ((wrow & 7) << 4))) =
                f2bu(sacc[nt][r] * sden[r]);
        }
    }

    // ---- O = P @ V : A from LDS (swizzled), B from global VT ----
    f32x4 oacc[8];
#pragma unroll
    for (int nt = 0; nt < 8; ++nt) oacc[nt] = f32x4{0.f, 0.f, 0.f, 0.f};
    const unsigned short* vtb = VT + (size_t)bh * C * W;
#pragma unroll
    for (int ks = 0; ks < 8; ++ks) {
        const int bcol = ks * 64 + l4 * 16;
        bf16x8 a = *reinterpret_cast<const bf16x8*>(
            pb + l15 * 512 + (bcol ^ ((l15 & 7) << 4)));
#pragma unroll
        for (int nt = 0; nt < 8; ++nt) {
            bf16x8 bv = *reinterpret_cast<const bf16x8*>(
                &vtb[(size_t)(nt * 16 + l15) * W + ks * 32 + l4 * 8]);
            oacc[nt] = __builtin_amdgcn_mfma_f32_16x16x32_bf16(a, bv, oacc[nt], 0, 0, 0);
        }
    }

    // ---- epilogue straight from accumulator layout: lane=channel, 16B/lane ----
#pragma unroll
    for (int nt = 0; nt < 8; ++nt) {
        const int c = nt * 16 + l15;
        const float cf = coef[c];
        const size_t g = (size_t)(b * C + c) * HW + (size_t)h * W + w0w + l4 * 4;
        float4 xv = *reinterpret_cast<const float4*>(&x[g]);
        float4 o;
        o.x = xv.x + oacc[nt][0] * cf;
        o.y = xv.y + oacc[nt][1] * cf;
        o.z = xv.z + oacc[nt][2] * cf;
        o.w = xv.w + oacc[nt][3] * cf;
        *reinterpret_cast<float4*>(&out[g]) = o;
    }
}

// ---------------------------------------------------------------------------
extern "C" void kernel_launch(void* const* d_in, const int* in_sizes, int n_in,
                              void* d_out, int out_size, void* d_ws, size_t ws_size,
                              hipStream_t stream) {
    (void)in_sizes; (void)n_in; (void)out_size; (void)ws_size;
    const float* x_l   = (const float*)d_in[0];
    const float* x_r   = (const float*)d_in[1];
    const float* Wl_m  = (const float*)d_in[2];
    const float* Wr_m  = (const float*)d_in[3];
    const float* dw_l  = (const float*)d_in[4];
    const float* dw_r  = (const float*)d_in[5];
    const float* lnl_w = (const float*)d_in[6];
    const float* lnl_b = (const float*)d_in[7];
    const float* lnr_w = (const float*)d_in[8];
    const float* lnr_b = (const float*)d_in[9];
    const float* Wq_l  = (const float*)d_in[10];
    const float* bq_l  = (const float*)d_in[11];
    const float* Wq_r  = (const float*)d_in[12];
    const float* bq_r  = (const float*)d_in[13];
    const float* beta  = (const float*)d_in[14];
    const float* gamma = (const float*)d_in[15];

    char* ws = (char*)d_ws;
    unsigned short* fusion_l = (unsigned short*)(ws + 0);            // 50,331,648
    unsigned short* fusion_r = (unsigned short*)(ws + 50331648);     // 50,331,648
    unsigned short* Q_l      = (unsigned short*)(ws + 100663296);    // 25,165,824
    unsigned short* Q_r      = (unsigned short*)(ws + 125829120);    // 25,165,824
    unsigned short* VT_l     = (unsigned short*)(ws + 150994944);    // 25,165,824
    unsigned short* VT_r     = (unsigned short*)(ws + 176160768);    // 25,165,824
    unsigned short* ymid     = (unsigned short*)(ws + 201326592);    // 50,331,648
    unsigned short* Wlb      = (unsigned short*)(ws + 251658240);    // 65,536
    unsigned short* Wrb      = (unsigned short*)(ws + 251723776);    // 65,536
    unsigned short* Wqlb     = (unsigned short*)(ws + 251789312);    // 32,768
    unsigned short* Wqrb     = (unsigned short*)(ws + 251822080);    // 32,768
    // xT buffers alias the VT region (dead once conv1x1 consumed them):
    unsigned short* xT_l     = VT_l;
    unsigned short* xT_r     = VT_r;

    float* out_l = (float*)d_out;
    float* out_r = out_l + (size_t)B * C * HW;

    const dim3 blk(256);

    wcvt_kernel<<<24, blk, 0, stream>>>(Wl_m, Wr_m, Wq_l, Wq_r, Wlb, Wrb, Wqlb, Wqrb);

    transpose_kernel<<<NPIX / 64, blk, 0, stream>>>(x_l, xT_l);
    conv1x1_mfma_kernel<<<1536, blk, 0, stream>>>(xT_l, Wlb, ymid);
    dwconv_kernel<<<BH * 4, blk, 0, stream>>>(ymid, dw_l, fusion_l);

    transpose_kernel<<<NPIX / 64, blk, 0, stream>>>(x_r, xT_r);
    conv1x1_mfma_kernel<<<1536, blk, 0, stream>>>(xT_r, Wrb, ymid);
    dwconv_kernel<<<BH * 4, blk, 0, stream>>>(ymid, dw_r, fusion_r);

    // VT overwrites xT (both consumed by now)
    vtrans_kernel<<<BH * 2, blk, 0, stream>>>(fusion_l, VT_l);
    vtrans_kernel<<<BH * 2, blk, 0, stream>>>(fusion_r, VT_r);

    lnq_kernel<<<NPIX / 64, blk, 0, stream>>>(fusion_l, lnl_w, lnl_b, Wqlb, bq_l, Q_l);
    lnq_kernel<<<NPIX / 64, blk, 0, stream>>>(fusion_r, lnr_w, lnr_b, Wqrb, bq_r, Q_r);

    // out_l = x_l + beta * softmax_row(Ql Qr^T) @ V_r
    fused_attn_kernel<<<768, dim3(512), 0, stream>>>(Q_l, Q_r, VT_r, x_l, beta, out_l);
    // out_r = x_r + gamma * softmax_row(Qr Ql^T) @ V_l
    fused_attn_kernel<<<768, dim3(512), 0, stream>>>(Q_r, Q_l, VT_l, x_r, gamma, out_r);
}

// Round 5
// 405.836 us; speedup vs baseline: 4.8454x; 1.1191x over previous
//
#include <hip/hip_runtime.h>
#include <hip/hip_bf16.h>

using bf16 = __hip_bfloat16;
typedef __attribute__((ext_vector_type(8))) short bf16x8;
typedef __attribute__((ext_vector_type(4))) float f32x4;

#define DEVI __device__ __forceinline__

constexpr int B = 4, C = 128, C2 = 256, H = 96, W = 256;
constexpr int HW = H * W;            // 24576
constexpr int NPIX = B * HW;         // 98304
constexpr int BH = B * H;            // 384
constexpr float SCALE = 0.08838834764831845f; // 128^-0.5
constexpr float LN_EPS = 1e-5f;

DEVI float lo16(unsigned u) { return __builtin_bit_cast(float, u << 16); }
DEVI float hi16(unsigned u) { return __builtin_bit_cast(float, u & 0xffff0000u); }
DEVI unsigned short f2bu(float v) {
    bf16 b = __float2bfloat16(v);
    return __builtin_bit_cast(unsigned short, b);
}
DEVI unsigned packbf2(float a, float b) {
    return (unsigned)f2bu(a) | ((unsigned)f2bu(b) << 16);
}

// ---------------------------------------------------------------------------
// W0: convert the 4 weight matrices fp32 -> bf16.
// ---------------------------------------------------------------------------
__global__ __launch_bounds__(256) void wcvt_kernel(
    const float* __restrict__ w0, const float* __restrict__ w1,
    const float* __restrict__ w2, const float* __restrict__ w3,
    unsigned short* __restrict__ o0, unsigned short* __restrict__ o1,
    unsigned short* __restrict__ o2, unsigned short* __restrict__ o3)
{
    const int id = blockIdx.x, t = threadIdx.x;
    const float* src; unsigned short* dst; int base;
    if (id < 8)       { src = w0; dst = o0; base = id * 4096; }
    else if (id < 16) { src = w1; dst = o1; base = (id - 8) * 4096; }
    else if (id < 20) { src = w2; dst = o2; base = (id - 16) * 4096; }
    else              { src = w3; dst = o3; base = (id - 20) * 4096; }
#pragma unroll
    for (int u = 0; u < 4; ++u) {
        int i = base + t * 16 + u * 4;
        float4 v = *reinterpret_cast<const float4*>(&src[i]);
        ushort4 o;
        o.x = f2bu(v.x); o.y = f2bu(v.y); o.z = f2bu(v.z); o.w = f2bu(v.w);
        *reinterpret_cast<ushort4*>(&dst[i]) = o;
    }
}

// ---------------------------------------------------------------------------
// T0: NCHW fp32 -> NHWC bf16 transpose/convert, both sides in one launch.
// ---------------------------------------------------------------------------
__global__ __launch_bounds__(256) void transpose_kernel(
    const float* __restrict__ x_l, const float* __restrict__ x_r,
    unsigned short* __restrict__ xT_l, unsigned short* __restrict__ xT_r)
{
    __shared__ unsigned short ts[64][132];
    const int side = blockIdx.x & 1;
    const int u = blockIdx.x >> 1;               // 0..1535
    const float* x = side ? x_r : x_l;
    unsigned short* xT = side ? xT_r : xT_l;
    const int t = threadIdx.x;
    const int b = u / (HW / 64);
    const int hw0 = (u % (HW / 64)) * 64;
#pragma unroll
    for (int i = 0; i < 8; ++i) {
        int idx = t + i * 256;
        int c = idx >> 4;
        int px = (idx & 15) * 4;
        float4 v = *reinterpret_cast<const float4*>(&x[((size_t)b * C + c) * HW + hw0 + px]);
        ts[px + 0][c] = f2bu(v.x);
        ts[px + 1][c] = f2bu(v.y);
        ts[px + 2][c] = f2bu(v.z);
        ts[px + 3][c] = f2bu(v.w);
    }
    __syncthreads();
#pragma unroll
    for (int i = 0; i < 8; ++i) {
        int idx = t + i * 256;
        int px = idx >> 5;
        int c4 = (idx & 31) * 4;
        ushort4 v = *reinterpret_cast<const ushort4*>(&ts[px][c4]);
        *reinterpret_cast<ushort4*>(&xT[(size_t)(b * HW + hw0 + px) * C + c4]) = v;
    }
}

// ---------------------------------------------------------------------------
// K1: conv1x1 as MFMA GEMM (bf16 weights), both sides.
// ---------------------------------------------------------------------------
__global__ __launch_bounds__(256) void conv1x1_mfma_kernel(
    const unsigned short* __restrict__ xT_l, const unsigned short* __restrict__ xT_r,
    const unsigned short* __restrict__ Wb_l, const unsigned short* __restrict__ Wb_r,
    unsigned short* __restrict__ y_l, unsigned short* __restrict__ y_r)
{
    const int side = blockIdx.x & 1;
    const int u = blockIdx.x >> 1;               // 0..1535
    const unsigned short* xT = side ? xT_r : xT_l;
    const unsigned short* Wb = side ? Wb_r : Wb_l;
    unsigned short* y = side ? y_r : y_l;

    const int t = threadIdx.x;
    const int lane = t & 63, wid = t >> 6;
    const int wr = wid >> 1, wc = wid & 1;
    const int l15 = lane & 15, l4 = lane >> 4;
    const int pxb = u % 768;
    const int ocb = u / 768;

    const int px_base = pxb * 128 + wr * 64 + l15;
    const int oc_base = ocb * 128 + wc * 64 + l15;

    f32x4 acc[4][4] = {};
    for (int kk = 0; kk < 4; ++kk) {
        const int k0 = kk * 32 + l4 * 8;
        bf16x8 a[4], bb[4];
#pragma unroll
        for (int mt = 0; mt < 4; ++mt)
            a[mt] = *reinterpret_cast<const bf16x8*>(&xT[(size_t)(px_base + mt * 16) * C + k0]);
#pragma unroll
        for (int nt = 0; nt < 4; ++nt)
            bb[nt] = *reinterpret_cast<const bf16x8*>(&Wb[(size_t)(oc_base + nt * 16) * C + k0]);
#pragma unroll
        for (int mt = 0; mt < 4; ++mt)
#pragma unroll
            for (int nt = 0; nt < 4; ++nt)
                acc[mt][nt] = __builtin_amdgcn_mfma_f32_16x16x32_bf16(a[mt], bb[nt], acc[mt][nt], 0, 0, 0);
    }
#pragma unroll
    for (int mt = 0; mt < 4; ++mt)
#pragma unroll
        for (int nt = 0; nt < 4; ++nt) {
            const int oc = ocb * 128 + wc * 64 + nt * 16 + l15;
#pragma unroll
            for (int r = 0; r < 4; ++r) {
                const int px = pxb * 128 + wr * 64 + mt * 16 + l4 * 4 + r;
                y[(size_t)px * C2 + oc] = f2bu(acc[mt][nt][r]);
            }
        }
}

// ---------------------------------------------------------------------------
// K2: depthwise 3x3 on NHWC bf16, both sides.
// V channels (c<128) -> VT[bh][c][w] (transposed via LDS, replaces vtrans)
// mid channels (c>=128) -> fusionM [NPIX][128]
// ---------------------------------------------------------------------------
__global__ __launch_bounds__(256) void dwconv_kernel(
    const unsigned short* __restrict__ y_l, const unsigned short* __restrict__ y_r,
    const float* __restrict__ dwk_l, const float* __restrict__ dwk_r,
    unsigned short* __restrict__ fm_l, unsigned short* __restrict__ fm_r,
    unsigned short* __restrict__ VT_l, unsigned short* __restrict__ VT_r)
{
    __shared__ unsigned short ts[64][128];   // V half, [w_local][c]
    const int side = blockIdx.x & 1;
    const int u = blockIdx.x >> 1;           // 0..1535
    const unsigned short* y = side ? y_r : y_l;
    const float* dwk = side ? dwk_r : dwk_l;
    unsigned short* fm = side ? fm_r : fm_l;
    unsigned short* VT = side ? VT_r : VT_l;

    const int t = threadIdx.x;
    const int wt = u & 3;
    const int bh = u >> 2;
    const int h = bh % H;
    const int ch8 = t & 31, wi = t >> 5;
    const int c0 = ch8 * 8;
    float wk[8][9];
#pragma unroll
    for (int j = 0; j < 8; ++j)
#pragma unroll
        for (int tap = 0; tap < 9; ++tap)
            wk[j][tap] = dwk[(c0 + j) * 9 + tap];
    const int wbase = wt * 64 + wi * 8;
    for (int i = 0; i < 8; ++i) {
        const int w = wbase + i;
        float acc[8] = {};
#pragma unroll
        for (int dh = 0; dh < 3; ++dh) {
            const int hh = h + dh - 1;
            if ((unsigned)hh >= (unsigned)H) continue;
#pragma unroll
            for (int dwi = 0; dwi < 3; ++dwi) {
                const int ww = w + dwi - 1;
                if ((unsigned)ww >= (unsigned)W) continue;
                const uint4 uu = *reinterpret_cast<const uint4*>(
                    &y[((size_t)(bh + dh - 1) * W + ww) * C2 + c0]);
                const unsigned arr[4] = {uu.x, uu.y, uu.z, uu.w};
#pragma unroll
                for (int k = 0; k < 4; ++k) {
                    acc[k * 2]     = fmaf(lo16(arr[k]), wk[k * 2][dh * 3 + dwi], acc[k * 2]);
                    acc[k * 2 + 1] = fmaf(hi16(arr[k]), wk[k * 2 + 1][dh * 3 + dwi], acc[k * 2 + 1]);
                }
            }
        }
        uint4 o;
        o.x = packbf2(acc[0], acc[1]); o.y = packbf2(acc[2], acc[3]);
        o.z = packbf2(acc[4], acc[5]); o.w = packbf2(acc[6], acc[7]);
        if (c0 < 128) {
            *reinterpret_cast<uint4*>(&ts[w - wt * 64][c0]) = o;     // V -> LDS
        } else {
            *reinterpret_cast<uint4*>(&fm[((size_t)bh * W + w) * C + (c0 - 128)]) = o;
        }
    }
    __syncthreads();
    // cooperative transposed write of V: VT[bh][c][wt*64 .. +63]
#pragma unroll
    for (int it = 0; it < 4; ++it) {
        const int idx = t + it * 256;        // 1024 tasks
        const int c = idx & 127, w8 = idx >> 7;   // w8: 0..7
        unsigned short vals[8];
#pragma unroll
        for (int k = 0; k < 8; ++k) vals[k] = ts[w8 * 8 + k][c];
        unsigned short* dst = &VT[((size_t)bh * C + c) * W + wt * 64 + w8 * 8];
        *reinterpret_cast<ushort4*>(dst)     = *reinterpret_cast<const ushort4*>(&vals[0]);
        *reinterpret_cast<ushort4*>(dst + 4) = *reinterpret_cast<const ushort4*>(&vals[4]);
    }
}

// ---------------------------------------------------------------------------
// K3: LayerNorm over C (on fusionM [NPIX][128]) + MFMA conv1x1 Q, both sides.
// ---------------------------------------------------------------------------
__global__ __launch_bounds__(256) void lnq_kernel(
    const unsigned short* __restrict__ fm_l, const unsigned short* __restrict__ fm_r,
    const float* __restrict__ lnw_l, const float* __restrict__ lnb_l,
    const float* __restrict__ lnw_r, const float* __restrict__ lnb_r,
    const unsigned short* __restrict__ Wq_l, const unsigned short* __restrict__ Wq_r,
    const float* __restrict__ bq_l, const float* __restrict__ bq_r,
    unsigned short* __restrict__ q_l, unsigned short* __restrict__ q_r)
{
    __shared__ float lnwb[256];
    __shared__ unsigned char msb[64 * 256];
    const int side = blockIdx.x & 1;
    const int u = blockIdx.x >> 1;           // 0..1535
    const unsigned short* fm = side ? fm_r : fm_l;
    const float* lnw = side ? lnw_r : lnw_l;
    const float* lnb = side ? lnb_r : lnb_l;
    const unsigned short* Wqb = side ? Wq_r : Wq_l;
    const float* bq = side ? bq_r : bq_l;
    unsigned short* q = side ? q_r : q_l;

    const int t = threadIdx.x;
    const int px0 = u * 64;
    lnwb[t] = (t < 128) ? lnw[t] : lnb[t - 128];

    const int px = t >> 2, qq = t & 3;
    const size_t pbase = (size_t)(px0 + px) * C + qq * 32;
    uint4 raw[4];
#pragma unroll
    for (int v = 0; v < 4; ++v)
        raw[v] = *reinterpret_cast<const uint4*>(&fm[pbase + v * 8]);
    float s1 = 0.f, s2 = 0.f;
#pragma unroll
    for (int v = 0; v < 4; ++v) {
        const unsigned arr[4] = {raw[v].x, raw[v].y, raw[v].z, raw[v].w};
#pragma unroll
        for (int k = 0; k < 4; ++k) {
            float v0 = lo16(arr[k]), v1 = hi16(arr[k]);
            s1 += v0 + v1; s2 += v0 * v0 + v1 * v1;
        }
    }
    s1 += __shfl_xor(s1, 1); s2 += __shfl_xor(s2, 1);
    s1 += __shfl_xor(s1, 2); s2 += __shfl_xor(s2, 2);
    const float mu = s1 * (1.f / C);
    const float rs = rsqrtf(s2 * (1.f / C) - mu * mu + LN_EPS);
    __syncthreads();
#pragma unroll
    for (int v = 0; v < 4; ++v) {
        const unsigned arr[4] = {raw[v].x, raw[v].y, raw[v].z, raw[v].w};
        float nv[8];
#pragma unroll
        for (int k = 0; k < 4; ++k) {
            int c = qq * 32 + v * 8 + k * 2;
            nv[k * 2]     = (lo16(arr[k]) - mu) * rs * lnwb[c] + lnwb[128 + c];
            nv[k * 2 + 1] = (hi16(arr[k]) - mu) * rs * lnwb[c + 1] + lnwb[128 + c + 1];
        }
        uint4 wv;
        wv.x = packbf2(nv[0], nv[1]); wv.y = packbf2(nv[2], nv[3]);
        wv.z = packbf2(nv[4], nv[5]); wv.w = packbf2(nv[6], nv[7]);
        unsigned addr = (unsigned)(px * 256 + qq * 64 + v * 16) ^ (unsigned)((px & 7) << 4);
        *reinterpret_cast<uint4*>(msb + addr) = wv;
    }
    __syncthreads();

    const int lane = t & 63, wid = t >> 6;
    const int l15 = lane & 15, l4 = lane >> 4;
    f32x4 acc[8] = {};
    for (int kk = 0; kk < 4; ++kk) {
        const int k0 = kk * 32 + l4 * 8;
        const int pxl = wid * 16 + l15;
        unsigned aaddr = (unsigned)(pxl * 256 + k0 * 2) ^ (unsigned)((pxl & 7) << 4);
        bf16x8 a = *reinterpret_cast<const bf16x8*>(msb + aaddr);
#pragma unroll
        for (int nt = 0; nt < 8; ++nt) {
            bf16x8 bv = *reinterpret_cast<const bf16x8*>(&Wqb[(size_t)(nt * 16 + l15) * C + k0]);
            acc[nt] = __builtin_amdgcn_mfma_f32_16x16x32_bf16(a, bv, acc[nt], 0, 0, 0);
        }
    }
#pragma unroll
    for (int nt = 0; nt < 8; ++nt) {
        const int oc = nt * 16 + l15;
        const float bias = bq[oc];
#pragma unroll
        for (int r = 0; r < 4; ++r) {
            const int pxr = px0 + wid * 16 + l4 * 4 + r;
            q[(size_t)pxr * C + oc] = f2bu(acc[nt][r] + bias);
        }
    }
}

// ---------------------------------------------------------------------------
// FUSED attention v3: both sides, 4-wave blocks, 64 q-rows, K chunked 2x128 v
// with online softmax; LDS 48KB -> 3 blocks/CU; coalesced LDS-transposed
// epilogue. Grid 3072, XCD-swizzled.
// ---------------------------------------------------------------------------
__global__ __launch_bounds__(256, 3) void fused_attn_kernel(
    const unsigned short* __restrict__ Q_l, const unsigned short* __restrict__ Q_r,
    const unsigned short* __restrict__ VT_l, const unsigned short* __restrict__ VT_r,
    const float* __restrict__ x_l, const float* __restrict__ x_r,
    const float* __restrict__ beta, const float* __restrict__ gamma,
    float* __restrict__ out_l, float* __restrict__ out_r)
{
    __shared__ __align__(16) unsigned char lds[49152];   // Kc 32KB + P 16KB
    const int bid = blockIdx.x;
    const int side = bid & 1;
    const int u = bid >> 1;              // 0..1535
    const int xcd = u & 7;
    const int g = u >> 3;                // 0..191
    const int bh = xcd * 48 + (g >> 2);
    const int quarter = g & 3;

    const unsigned short* Q  = side ? Q_r : Q_l;
    const unsigned short* K  = side ? Q_l : Q_r;
    const unsigned short* VT = side ? VT_l : VT_r;
    const float* x    = side ? x_r : x_l;
    const float* coef = side ? gamma : beta;
    float* out        = side ? out_r : out_l;

    const int t = threadIdx.x;
    const int lane = t & 63, wv = t >> 6;
    const int l15 = lane & 15, l4 = lane >> 4;
    const int b = bh / H, h = bh % H;
    const int w0w = quarter * 64 + wv * 16;   // this wave's first q-row

    // ---- stage chunk 0 of K (rows v0..v0+127) into LDS, swizzled source ----
    const char* kgb = (const char*)(K + (size_t)bh * W * C);
    const int rowl = lane >> 4;
    const int cb = (lane & 15) * 16;
    {
#pragma unroll
        for (int i = 0; i < 8; ++i) {
            const int r0 = wv * 32 + i * 4;
            const int row = r0 + rowl;
            const char* src = kgb + row * 256 + (cb ^ ((row & 7) << 4));
            __builtin_amdgcn_global_load_lds(
                (const __attribute__((address_space(1))) void*)src,
                (__attribute__((address_space(3))) void*)(lds + r0 * 256), 16, 0, 0);
        }
    }

    // ---- Q fragments ----
    const size_t qrow = ((size_t)bh * W + w0w + l15) * C;
    bf16x8 qa[4];
#pragma unroll
    for (int ks = 0; ks < 4; ++ks)
        qa[ks] = *reinterpret_cast<const bf16x8*>(&Q[qrow + ks * 32 + l4 * 8]);

    __syncthreads();   // chunk0 staged

    float mrow[4] = {-1e30f, -1e30f, -1e30f, -1e30f};
    float srow[4] = {0.f, 0.f, 0.f, 0.f};
    f32x4 oacc[8];
#pragma unroll
    for (int nt = 0; nt < 8; ++nt) oacc[nt] = f32x4{0.f, 0.f, 0.f, 0.f};
    unsigned char* pb = lds + 32768 + wv * 4096;
    const unsigned short* vtb = VT + (size_t)bh * C * W;

#pragma unroll
    for (int ci = 0; ci < 2; ++ci) {
        // ---- QK chunk: S[16 x 128] ----
        f32x4 sacc[8];
#pragma unroll
        for (int nt = 0; nt < 8; ++nt) sacc[nt] = f32x4{0.f, 0.f, 0.f, 0.f};
#pragma unroll
        for (int ks = 0; ks < 4; ++ks) {
            const int bcol = ks * 64 + l4 * 16;
#pragma unroll
            for (int nt = 0; nt < 8; ++nt) {
                const int v = nt * 16 + l15;
                bf16x8 bv = *reinterpret_cast<const bf16x8*>(
                    lds + v * 256 + (bcol ^ ((v & 7) << 4)));
                sacc[nt] = __builtin_amdgcn_mfma_f32_16x16x32_bf16(qa[ks], bv, sacc[nt], 0, 0, 0);
            }
        }
        __syncthreads();   // everyone done reading Kc
        if (ci == 0) {     // prefetch chunk 1 under softmax+PV
#pragma unroll
            for (int i = 0; i < 8; ++i) {
                const int r0 = wv * 32 + i * 4;
                const int row = r0 + rowl;
                const char* src = kgb + (128 + row) * 256 + (cb ^ ((row & 7) << 4));
                __builtin_amdgcn_global_load_lds(
                    (const __attribute__((address_space(1))) void*)src,
                    (__attribute__((address_space(3))) void*)(lds + r0 * 256), 16, 0, 0);
            }
        }

        // ---- online softmax update ----
        float corr[4];
#pragma unroll
        for (int r = 0; r < 4; ++r) {
            float mx = -1e30f;
#pragma unroll
            for (int nt = 0; nt < 8; ++nt) {
                sacc[nt][r] *= SCALE;
                mx = fmaxf(mx, sacc[nt][r]);
            }
#pragma unroll
            for (int off = 1; off <= 8; off <<= 1) mx = fmaxf(mx, __shfl_xor(mx, off));
            const float mnew = fmaxf(mrow[r], mx);
            corr[r] = __expf(mrow[r] - mnew);
            mrow[r] = mnew;
            float ps = 0.f;
#pragma unroll
            for (int nt = 0; nt < 8; ++nt) {
                float e = __expf(sacc[nt][r] - mnew);
                sacc[nt][r] = e;
                ps += e;
            }
#pragma unroll
            for (int off = 1; off <= 8; off <<= 1) ps += __shfl_xor(ps, off);
            srow[r] = srow[r] * corr[r] + ps;
        }
#pragma unroll
        for (int nt = 0; nt < 8; ++nt)
#pragma unroll
            for (int r = 0; r < 4; ++r) oacc[nt][r] *= corr[r];

        // ---- write P (unnormalized) to own LDS slice, swizzled ----
#pragma unroll
        for (int nt = 0; nt < 8; ++nt) {
            const int vc = nt * 16 + l15;
#pragma unroll
            for (int r = 0; r < 4; ++r) {
                const int wr = l4 * 4 + r;
                *(unsigned short*)(pb + wr * 256 + ((vc * 2) ^ ((wr & 7) << 4))) =
                    f2bu(sacc[nt][r]);
            }
        }

        // ---- PV chunk: O += P[16x128] @ V[128x128] ----
#pragma unroll
        for (int kk = 0; kk < 4; ++kk) {
            const int bcol = kk * 64 + l4 * 16;
            bf16x8 a = *reinterpret_cast<const bf16x8*>(
                pb + l15 * 256 + (bcol ^ ((l15 & 7) << 4)));
#pragma unroll
            for (int nt = 0; nt < 8; ++nt) {
                bf16x8 bv = *reinterpret_cast<const bf16x8*>(
                    &vtb[(size_t)(nt * 16 + l15) * W + ci * 128 + kk * 32 + l4 * 8]);
                oacc[nt] = __builtin_amdgcn_mfma_f32_16x16x32_bf16(a, bv, oacc[nt], 0, 0, 0);
            }
        }
        __syncthreads();   // chunk boundary: next stage data landed / Kc free
    }

    // ---- epilogue: O/s -> LDS f32 [64 w][128 c], then coalesced out ----
    float inv[4];
#pragma unroll
    for (int r = 0; r < 4; ++r) inv[r] = 1.f / srow[r];
    float* ob = (float*)lds;
#pragma unroll
    for (int nt = 0; nt < 8; ++nt) {
        const int c = nt * 16 + l15;
#pragma unroll
        for (int r = 0; r < 4; ++r)
            ob[(wv * 16 + l4 * 4 + r) * 128 + c] = oacc[nt][r] * inv[r];
    }
    __syncthreads();

    const int c = t >> 1, hf = t & 1;
    const float cf = coef[c];
    const size_t gbase = (size_t)(b * C + c) * HW + (size_t)h * W + quarter * 64 + hf * 32;
#pragma unroll
    for (int w4 = 0; w4 < 8; ++w4) {
        float4 xv = *reinterpret_cast<const float4*>(&x[gbase + w4 * 4]);
        float4 ov;
        ov.x = ob[(hf * 32 + w4 * 4 + 0) * 128 + c];
        ov.y = ob[(hf * 32 + w4 * 4 + 1) * 128 + c];
        ov.z = ob[(hf * 32 + w4 * 4 + 2) * 128 + c];
        ov.w = ob[(hf * 32 + w4 * 4 + 3) * 128 + c];
        float4 o;
        o.x = xv.x + ov.x * cf; o.y = xv.y + ov.y * cf;
        o.z = xv.z + ov.z * cf; o.w = xv.w + ov.w * cf;
        *reinterpret_cast<float4*>(&out[gbase + w4 * 4]) = o;
    }
}

// ---------------------------------------------------------------------------
extern "C" void kernel_launch(void* const* d_in, const int* in_sizes, int n_in,
                              void* d_out, int out_size, void* d_ws, size_t ws_size,
                              hipStream_t stream) {
    (void)in_sizes; (void)n_in; (void)out_size; (void)ws_size;
    const float* x_l   = (const float*)d_in[0];
    const float* x_r   = (const float*)d_in[1];
    const float* Wl_m  = (const float*)d_in[2];
    const float* Wr_m  = (const float*)d_in[3];
    const float* dw_l  = (const float*)d_in[4];
    const float* dw_r  = (const float*)d_in[5];
    const float* lnl_w = (const float*)d_in[6];
    const float* lnl_b = (const float*)d_in[7];
    const float* lnr_w = (const float*)d_in[8];
    const float* lnr_b = (const float*)d_in[9];
    const float* Wq_l  = (const float*)d_in[10];
    const float* bq_l  = (const float*)d_in[11];
    const float* Wq_r  = (const float*)d_in[12];
    const float* bq_r  = (const float*)d_in[13];
    const float* beta  = (const float*)d_in[14];
    const float* gamma = (const float*)d_in[15];

    char* ws = (char*)d_ws;
    unsigned short* ymid_l   = (unsigned short*)(ws + 0);            // 50,331,648
    unsigned short* ymid_r   = (unsigned short*)(ws + 50331648);     // 50,331,648
    unsigned short* fm_l     = (unsigned short*)(ws + 100663296);    // 25,165,824
    unsigned short* fm_r     = (unsigned short*)(ws + 125829120);    // 25,165,824
    unsigned short* VT_l     = (unsigned short*)(ws + 150994944);    // 25,165,824
    unsigned short* VT_r     = (unsigned short*)(ws + 176160768);    // 25,165,824
    unsigned short* Q_l      = (unsigned short*)(ws + 201326592);    // 25,165,824
    unsigned short* Q_r      = (unsigned short*)(ws + 226492416);    // 25,165,824
    unsigned short* Wlb      = (unsigned short*)(ws + 251658240);    // 65,536
    unsigned short* Wrb      = (unsigned short*)(ws + 251723776);    // 65,536
    unsigned short* Wqlb     = (unsigned short*)(ws + 251789312);    // 32,768
    unsigned short* Wqrb     = (unsigned short*)(ws + 251822080);    // 32,768
    // xT buffers alias Q region (dead once conv1x1 consumed them; Q written later)
    unsigned short* xT_l     = Q_l;
    unsigned short* xT_r     = Q_r;

    float* out_l = (float*)d_out;
    float* out_r = out_l + (size_t)B * C * HW;

    const dim3 blk(256);

    wcvt_kernel<<<24, blk, 0, stream>>>(Wl_m, Wr_m, Wq_l, Wq_r, Wlb, Wrb, Wqlb, Wqrb);

    transpose_kernel<<<3072, blk, 0, stream>>>(x_l, x_r, xT_l, xT_r);
    conv1x1_mfma_kernel<<<3072, blk, 0, stream>>>(xT_l, xT_r, Wlb, Wrb, ymid_l, ymid_r);
    dwconv_kernel<<<3072, blk, 0, stream>>>(ymid_l, ymid_r, dw_l, dw_r,
                                            fm_l, fm_r, VT_l, VT_r);
    lnq_kernel<<<3072, blk, 0, stream>>>(fm_l, fm_r, lnl_w, lnl_b, lnr_w, lnr_b,
                                         Wqlb, Wqrb, bq_l, bq_r, Q_l, Q_r);
    fused_attn_kernel<<<3072, blk, 0, stream>>>(Q_l, Q_r, VT_l, VT_r,
                                                x_l, x_r, beta, gamma, out_l, out_r);
}